// Round 3
// baseline (547.272 us; speedup 1.0000x reference)
//
#include <hip/hip_runtime.h>

namespace {

typedef short s16x8 __attribute__((ext_vector_type(8)));
typedef float f32x4 __attribute__((ext_vector_type(4)));

__device__ __forceinline__ float bf2f(unsigned short u) {
  return __uint_as_float(((unsigned)u) << 16);
}
__device__ __forceinline__ unsigned short f2bf(float f) {
  unsigned u = __float_as_uint(f);
  u += 0x7fffu + ((u >> 16) & 1u);
  return (unsigned short)(u >> 16);
}

// async global->LDS, 16B per lane. LDS dest is wave-uniform base + lane*16.
typedef __attribute__((address_space(3))) unsigned int lds_u32;
typedef __attribute__((address_space(1))) const unsigned int glob_u32;
__device__ __forceinline__ void gl16(const void* g, void* l) {
  __builtin_amdgcn_global_load_lds((glob_u32*)g, (lds_u32*)l, 16, 0, 0);
}

// x (fp32) -> xb (bf16), 35000x512 total; xb lives in d_out (dead until final_mfma3).
__global__ __launch_bounds__(256) void cvt_x3(const float* __restrict__ x0,
                                              const float* __restrict__ x1,
                                              const float* __restrict__ x2,
                                              unsigned short* __restrict__ out) {
  size_t i = ((size_t)blockIdx.x * 256 + threadIdx.x) * 8;
  const float* src;
  size_t off;
  if (i < (size_t)20000 * 512) { src = x0; off = i; }
  else if (i < (size_t)30000 * 512) { src = x1; off = i - (size_t)20000 * 512; }
  else { src = x2; off = i - (size_t)30000 * 512; }
  float4 a = *(const float4*)(src + off);
  float4 b = *(const float4*)(src + off + 4);
  s16x8 v;
  v[0] = (short)f2bf(a.x); v[1] = (short)f2bf(a.y);
  v[2] = (short)f2bf(a.z); v[3] = (short)f2bf(a.w);
  v[4] = (short)f2bf(b.x); v[5] = (short)f2bf(b.y);
  v[6] = (short)f2bf(b.z); v[7] = (short)f2bf(b.w);
  *(s16x8*)(out + i) = v;
}

// fp32 [R][256] -> bf16 [256][R] (transposed). wsh: R=256, wcat: R=512.
struct Tc6 { const float* src[6]; unsigned short* dst[6]; int R[6]; };
__global__ __launch_bounds__(256) void transpose_cvt(Tc6 a) {
  int mat = blockIdx.z;
  int R = a.R[mat];
  int r0 = blockIdx.y * 32, c0 = blockIdx.x * 32;
  if (r0 >= R) return;
  const float* __restrict__ src = a.src[mat];
  unsigned short* __restrict__ dst = a.dst[mat];
  __shared__ float T[32][33];
  int tx = threadIdx.x & 31, ty = threadIdx.x >> 5;
  #pragma unroll
  for (int j = 0; j < 4; ++j) {
    int r = ty + j * 8;
    T[r][tx] = src[(size_t)(r0 + r) * 256 + c0 + tx];
  }
  __syncthreads();
  #pragma unroll
  for (int j = 0; j < 4; ++j) {
    int c = ty + j * 8;
    dst[(size_t)(c0 + c) * R + r0 + tx] = f2bf(T[tx][c]);
  }
}

// Wcbt[256x512] = wshT[256x256](bf16) @ W[512x256]^T(fp32, cvt on load)
struct Comb9 { const unsigned short* A[9]; const float* B[9]; unsigned short* C[9]; };
__global__ __launch_bounds__(256) void combine_mfma(Comb9 g) {
  int z = blockIdx.z;
  const unsigned short* __restrict__ A = g.A[z];
  const float* __restrict__ B = g.B[z];
  unsigned short* __restrict__ C = g.C[z];
  int row0 = blockIdx.y * 128;
  int col0 = blockIdx.x * 128;
  __shared__ unsigned short As[128 * 40];
  __shared__ unsigned short Bs[128 * 40];
  int tid = threadIdx.x, lane = tid & 63, w = tid >> 6;
  int quad = lane >> 4, m16 = lane & 15;
  f32x4 acc[2][8];
  #pragma unroll
  for (int r = 0; r < 2; ++r)
    #pragma unroll
    for (int c = 0; c < 8; ++c) acc[r][c] = (f32x4){0.f, 0.f, 0.f, 0.f};
  for (int k0 = 0; k0 < 256; k0 += 32) {
    #pragma unroll
    for (int i = 0; i < 2; ++i) {
      int ch = tid + i * 256;
      int m = ch >> 2, kk = (ch & 3) * 8;
      *(s16x8*)&As[m * 40 + kk] = *(const s16x8*)(A + (size_t)(row0 + m) * 256 + k0 + kk);
      const float4* bp = (const float4*)(B + (size_t)(col0 + m) * 256 + k0 + kk);
      float4 b0 = bp[0], b1 = bp[1];
      s16x8 bv;
      bv[0] = (short)f2bf(b0.x); bv[1] = (short)f2bf(b0.y);
      bv[2] = (short)f2bf(b0.z); bv[3] = (short)f2bf(b0.w);
      bv[4] = (short)f2bf(b1.x); bv[5] = (short)f2bf(b1.y);
      bv[6] = (short)f2bf(b1.z); bv[7] = (short)f2bf(b1.w);
      *(s16x8*)&Bs[m * 40 + kk] = bv;
    }
    __syncthreads();
    s16x8 af[2], bf[8];
    #pragma unroll
    for (int r = 0; r < 2; ++r)
      af[r] = *(const s16x8*)&As[(w * 32 + r * 16 + m16) * 40 + quad * 8];
    #pragma unroll
    for (int c = 0; c < 8; ++c)
      bf[c] = *(const s16x8*)&Bs[(c * 16 + m16) * 40 + quad * 8];
    #pragma unroll
    for (int r = 0; r < 2; ++r)
      #pragma unroll
      for (int c = 0; c < 8; ++c)
        acc[r][c] = __builtin_amdgcn_mfma_f32_16x16x32_bf16(af[r], bf[c], acc[r][c], 0, 0, 0);
    __syncthreads();
  }
  #pragma unroll
  for (int r = 0; r < 2; ++r)
    #pragma unroll
    for (int i = 0; i < 4; ++i) {
      int row = row0 + w * 32 + r * 16 + quad * 4 + i;
      #pragma unroll
      for (int c = 0; c < 8; ++c)
        C[(size_t)row * 512 + col0 + c * 16 + m16] = f2bf(acc[r][c][i]);
    }
}

// 9 projections, one launch. m97 structure: 128x128 tile, BK=32, 4 waves x 64x64,
// single-buffered linear LDS, global_load_lds width-16 for both A (bf16) and B (bf16).
struct Proj9 { const unsigned short* A[9]; const unsigned short* Bt[9]; unsigned short* C[9]; int M[9]; };
__global__ __launch_bounds__(256) void proj_mfma9(Proj9 g) {
  int z = blockIdx.z;
  int M = g.M[z];
  int row0 = blockIdx.y * 128;
  if (row0 >= M) return;
  int col0 = blockIdx.x * 128;
  const unsigned short* __restrict__ A = g.A[z];
  const unsigned short* __restrict__ Bt = g.Bt[z];
  unsigned short* __restrict__ C = g.C[z];
  __shared__ unsigned short As[128 * 32];
  __shared__ unsigned short Bs[128 * 32];
  int tid = threadIdx.x, lane = tid & 63, w = tid >> 6;
  int quad = lane >> 4, m16 = lane & 15;
  int lr = lane >> 2, lk = (lane & 3) * 8;
  int r0g = row0 + w * 32 + lr;
  int r1g = r0g + 16;
  const unsigned short* a0p = A + (size_t)(r0g < M ? r0g : M - 1) * 512 + lk;
  const unsigned short* a1p = A + (size_t)(r1g < M ? r1g : M - 1) * 512 + lk;
  const unsigned short* b0p = Bt + (size_t)(col0 + w * 32 + lr) * 512 + lk;
  const unsigned short* b1p = b0p + (size_t)16 * 512;
  unsigned short* as0 = &As[w * 1024];
  unsigned short* as1 = &As[w * 1024 + 512];
  unsigned short* bs0 = &Bs[w * 1024];
  unsigned short* bs1 = &Bs[w * 1024 + 512];
  int wr = (w & 1) * 64, wc = (w >> 1) * 64;
  f32x4 acc[4][4];
  #pragma unroll
  for (int r = 0; r < 4; ++r)
    #pragma unroll
    for (int c = 0; c < 4; ++c) acc[r][c] = (f32x4){0.f, 0.f, 0.f, 0.f};
  for (int k0 = 0; k0 < 512; k0 += 32) {
    gl16(a0p + k0, as0);
    gl16(a1p + k0, as1);
    gl16(b0p + k0, bs0);
    gl16(b1p + k0, bs1);
    __syncthreads();
    s16x8 af[4], bf[4];
    #pragma unroll
    for (int r = 0; r < 4; ++r)
      af[r] = *(const s16x8*)&As[(wr + r * 16 + m16) * 32 + quad * 8];
    #pragma unroll
    for (int c = 0; c < 4; ++c)
      bf[c] = *(const s16x8*)&Bs[(wc + c * 16 + m16) * 32 + quad * 8];
    #pragma unroll
    for (int r = 0; r < 4; ++r)
      #pragma unroll
      for (int c = 0; c < 4; ++c)
        acc[r][c] = __builtin_amdgcn_mfma_f32_16x16x32_bf16(af[r], bf[c], acc[r][c], 0, 0, 0);
    __syncthreads();
  }
  #pragma unroll
  for (int r = 0; r < 4; ++r)
    #pragma unroll
    for (int i = 0; i < 4; ++i) {
      int row = row0 + wr + r * 16 + quad * 4 + i;
      if (row < M) {
        #pragma unroll
        for (int c = 0; c < 4; ++c)
          C[(size_t)row * 256 + col0 + wc + c * 16 + m16] = f2bf(acc[r][c][i]);
      }
    }
}

struct Edges6 { const int* src[6]; const int* dst[6]; const float* w[6]; int nE[6]; int cbase[6]; };

// ---- CSR build: two-level, XCD-local counting sort ----
// Level 1 (binscat, fused histogram): per edge, bump fine per-dst count AND
// scatter an 8B record {gdst, pay} into cell (bucket = gdst>>6, sub = linBlk&7).
// sub tracks the round-robin block->XCD mapping, so each cell's contiguous
// region is written by ONE XCD -> lines accumulate in its L2 (no 16x write
// amplification like the old direct 4B scatter).
#define RSH 6
#define NBUK 1094          // ceil(70000/64)
#define RCAP 224           // cell mean 128, std ~11 -> 8.5 sigma + overflow path
#define NOV 65536

__global__ __launch_bounds__(256) void binscat(Edges6 ep, int* __restrict__ counts,
                                               int* __restrict__ subcnt, int* __restrict__ ovcnt,
                                               unsigned long long* __restrict__ rec,
                                               unsigned long long* __restrict__ ovbuf) {
  int rho = blockIdx.y;
  int e = blockIdx.x * 256 + threadIdx.x;
  if (e >= ep.nE[rho]) return;
  int sub = (blockIdx.y * gridDim.x + blockIdx.x) & 7;  // XCD proxy (perf-only)
  int gd = ep.cbase[rho] + ep.dst[rho][e];
  atomicAdd(&counts[gd], 1);
  unsigned pay = (((unsigned)f2bf(ep.w[rho][e])) << 16) | (unsigned)ep.src[rho][e];
  unsigned long long r = ((unsigned long long)(unsigned)gd << 32) | pay;
  int cell = (gd >> RSH) * 8 + sub;
  int pos = atomicAdd(&subcnt[cell], 1);
  if (pos < RCAP) rec[(size_t)cell * RCAP + pos] = r;
  else { int op = atomicAdd(ovcnt, 1); ovbuf[op & (NOV - 1)] = r; }
}

__global__ __launch_bounds__(256) void scan1(const int* __restrict__ cnt, int* __restrict__ out,
                                             int* __restrict__ part, int len) {
  __shared__ int sh[256];
  int base = blockIdx.x * 2048 + threadIdx.x * 8;
  int v[8];
  int s = 0;
  #pragma unroll
  for (int j = 0; j < 8; ++j) {
    int i = base + j;
    int x = (i < len) ? cnt[i] : 0;
    v[j] = s;
    s += x;
  }
  sh[threadIdx.x] = s;
  __syncthreads();
  for (int off = 1; off < 256; off <<= 1) {
    int t = (threadIdx.x >= off) ? sh[threadIdx.x - off] : 0;
    __syncthreads();
    sh[threadIdx.x] += t;
    __syncthreads();
  }
  int texcl = sh[threadIdx.x] - s;
  #pragma unroll
  for (int j = 0; j < 8; ++j) {
    int i = base + j;
    if (i < len) out[i] = texcl + v[j];
  }
  if (threadIdx.x == 255) part[blockIdx.x] = sh[255];
}

__global__ void scan2(int* __restrict__ part, int nb, int* __restrict__ total_out) {
  __shared__ int sh[64];
  int t = threadIdx.x;
  int v = (t < nb) ? part[t] : 0;
  sh[t] = v;
  __syncthreads();
  for (int off = 1; off < 64; off <<= 1) {
    int x = (t >= off) ? sh[t - off] : 0;
    __syncthreads();
    sh[t] += x;
    __syncthreads();
  }
  if (t < nb) part[t] = sh[t] - v;
  if (t == 63) *total_out = sh[63];
}

__global__ __launch_bounds__(256) void scan3(int* __restrict__ offs,
                                             const int* __restrict__ part, int len) {
  int i = blockIdx.x * 256 + threadIdx.x;
  if (i >= len) return;
  offs[i] += part[i >> 11];
}

// Level 2: one block per bucket; LDS cursors from offs; each record gets its
// final CSR slot via LDS atomic; writes land in the bucket's contiguous
// ~4KB csr_pay window -> dense in time -> no HBM write amplification.
__global__ __launch_bounds__(256) void fine_fill(const int* __restrict__ offs,
                                                 const int* __restrict__ subcnt,
                                                 const unsigned long long* __restrict__ rec,
                                                 const int* __restrict__ ovcnt,
                                                 const unsigned long long* __restrict__ ovbuf,
                                                 unsigned int* __restrict__ pay) {
  int b = blockIdx.x;
  __shared__ int cur[64];
  int t = threadIdx.x;
  if (t < 64) {
    int gd = (b << RSH) + t;
    cur[t] = (gd < 70000) ? offs[gd] : 0;
  }
  __syncthreads();
  #pragma unroll 1
  for (int s = 0; s < 8; ++s) {
    int cell = b * 8 + s;
    int cnt = subcnt[cell];
    cnt = cnt < RCAP ? cnt : RCAP;
    const unsigned long long* rp = rec + (size_t)cell * RCAP;
    for (int i = t; i < cnt; i += 256) {
      unsigned long long r = rp[i];
      int ld = (int)(r >> 32) & 63;
      int pos = atomicAdd(&cur[ld], 1);
      pay[pos] = (unsigned)r;
    }
  }
  int ovn = *ovcnt;
  ovn = ovn < NOV ? ovn : NOV;
  for (int i = t; i < ovn; i += 256) {
    unsigned long long r = ovbuf[i];
    int gd = (int)(r >> 32);
    if ((gd >> RSH) == b) {
      int pos = atomicAdd(&cur[gd & 63], 1);
      pay[pos] = (unsigned)r;
    }
  }
}

// all 6 relations; one wave per (dst, rel); 4 edges in flight (2 per half-wave)
struct Gather6 { const unsigned short* proj[6]; unsigned short* out[6]; int cb[6]; int n[6]; };
__global__ __launch_bounds__(256) void gather_all(Gather6 g, const int* __restrict__ offs,
                                                  const unsigned int* __restrict__ pay) {
  int rho = blockIdx.y;
  int n = g.n[rho];
  int d = blockIdx.x * 4 + (threadIdx.x >> 6);
  if (d >= n) return;
  int lane = threadIdx.x & 63, half = lane >> 5, l32 = lane & 31;
  const unsigned short* __restrict__ proj = g.proj[rho];
  const int* of = offs + g.cb[rho];
  int s0 = of[d], s1 = of[d + 1];
  float acc[8] = {};
  int e = s0 + half;
  for (; e + 2 < s1; e += 4) {
    unsigned int u0 = pay[e], u1 = pay[e + 2];
    float wt0 = bf2f((unsigned short)(u0 >> 16));
    float wt1 = bf2f((unsigned short)(u1 >> 16));
    s16x8 v0 = *(const s16x8*)(proj + (size_t)(u0 & 0xffffu) * 256 + l32 * 8);
    s16x8 v1 = *(const s16x8*)(proj + (size_t)(u1 & 0xffffu) * 256 + l32 * 8);
    #pragma unroll
    for (int j = 0; j < 8; ++j) {
      acc[j] = fmaf(bf2f((unsigned short)v0[j]), wt0, acc[j]);
      acc[j] = fmaf(bf2f((unsigned short)v1[j]), wt1, acc[j]);
    }
  }
  if (e < s1) {
    unsigned int u = pay[e];
    float wt = bf2f((unsigned short)(u >> 16));
    s16x8 v = *(const s16x8*)(proj + (size_t)(u & 0xffffu) * 256 + l32 * 8);
    #pragma unroll
    for (int j = 0; j < 8; ++j) acc[j] = fmaf(bf2f((unsigned short)v[j]), wt, acc[j]);
  }
  #pragma unroll
  for (int j = 0; j < 8; ++j) acc[j] += __shfl(acc[j], lane ^ 32, 64);
  if (half == 0) {
    s16x8 o;
    #pragma unroll
    for (int j = 0; j < 8; ++j) o[j] = (short)f2bf(acc[j]);
    *(s16x8*)(g.out[rho] + (size_t)d * 256 + l32 * 8) = o;
  }
}

// all 3 types: scores + FAITHFUL reshape(n,2) softmax over adjacent e-pairs
struct Att3 { const unsigned short* nb[3]; const unsigned short* self[3];
              const float* watt[3]; float* att[3]; int n[3]; };
__global__ __launch_bounds__(256) void e_att3(Att3 g) {
  int z = blockIdx.z;
  int n = g.n[z];
  int wv = threadIdx.x >> 6;
  int idx = blockIdx.x * 4 + wv;
  int lane = threadIdx.x & 63;
  __shared__ float ev[4];
  float sum = 0.f;
  if (idx < 2 * n) {
    int i = idx < n ? idx : idx - n;
    ushort4 v  = *(const ushort4*)(g.nb[z] + (size_t)idx * 256 + (lane << 2));
    ushort4 sv = *(const ushort4*)(g.self[z] + (size_t)i * 256 + (lane << 2));
    float4 wa = *(const float4*)(g.watt[z] + (lane << 2));
    float4 wb = *(const float4*)(g.watt[z] + 256 + (lane << 2));
    sum = bf2f(v.x) * wa.x + bf2f(v.y) * wa.y + bf2f(v.z) * wa.z + bf2f(v.w) * wa.w +
          bf2f(sv.x) * wb.x + bf2f(sv.y) * wb.y + bf2f(sv.z) * wb.z + bf2f(sv.w) * wb.w;
    #pragma unroll
    for (int off = 32; off > 0; off >>= 1) sum += __shfl_down(sum, off, 64);
  }
  if (lane == 0) ev[wv] = sum;
  __syncthreads();
  if (threadIdx.x < 2) {
    int base = blockIdx.x * 4 + threadIdx.x * 2;
    if (base < 2 * n) {
      float f0 = ev[threadIdx.x * 2], f1 = ev[threadIdx.x * 2 + 1];
      f0 = f0 > 0.f ? f0 : 0.01f * f0;
      f1 = f1 > 0.f ? f1 : 0.01f * f1;
      float m = fmaxf(f0, f1);
      float a = expf(f0 - m), b = expf(f1 - m);
      float inv = 1.f / (a + b);
      g.att[z][base] = a * inv;
      g.att[z][base + 1] = b * inv;
    }
  }
}

// all 3 types, BM=64/BN=256, 64x64 wave tiles, pipelined staging.
struct Fin3 { const unsigned short* nb[3]; const unsigned short* self[3]; const float* att[3];
              const unsigned short* Wt[3]; const float* bias[3]; float* out[3]; int M[3]; };
__global__ __launch_bounds__(256, 3) void final_mfma3(Fin3 g) {
  int z = blockIdx.z;
  int M = g.M[z];
  int row0 = blockIdx.y * 64;
  if (row0 >= M) return;
  const unsigned short* __restrict__ nbft = g.nb[z];
  const unsigned short* __restrict__ selfb = g.self[z];
  const float* __restrict__ att = g.att[z];
  const unsigned short* __restrict__ Wt = g.Wt[z];
  __shared__ unsigned short As[64 * 40];
  __shared__ unsigned short Bs[256 * 40];
  int tid = threadIdx.x, lane = tid & 63, w = tid >> 6;
  int quad = lane >> 4, m16 = lane & 15;
  int am = tid >> 2, akk = (tid & 3) * 8;
  int gr = row0 + am;
  float a0 = 0.f, a1 = 0.f;
  if (gr < M) { a0 = att[2 * gr]; a1 = att[2 * gr + 1]; }
  f32x4 acc[4][4];
  #pragma unroll
  for (int r = 0; r < 4; ++r)
    #pragma unroll
    for (int c = 0; c < 4; ++c) acc[r][c] = (f32x4){0.f, 0.f, 0.f, 0.f};

  s16x8 pu0 = {}, pu1 = {};
  s16x8 pb[4];

  auto loadA = [&](int k0) {
    int kg = k0 + akk;
    if (gr < M) {
      if (kg < 256) {
        pu0 = *(const s16x8*)(nbft + (size_t)gr * 256 + kg);
        pu1 = *(const s16x8*)(nbft + ((size_t)M + gr) * 256 + kg);
      } else {
        pu0 = *(const s16x8*)(selfb + (size_t)gr * 256 + (kg - 256));
      }
    }
  };
  auto loadB = [&](int k0) {
    #pragma unroll
    for (int i = 0; i < 4; ++i) {
      int ch = tid + i * 256;
      int m = ch >> 2, kk = (ch & 3) * 8;
      pb[i] = *(const s16x8*)(Wt + (size_t)m * 512 + k0 + kk);
    }
  };
  auto storeLDS = [&](int k0) {
    int kg = k0 + akk;
    s16x8 v = {};
    if (gr < M) {
      if (kg < 256) {
        #pragma unroll
        for (int j = 0; j < 8; ++j)
          v[j] = (short)f2bf(fmaf(a0, bf2f((unsigned short)pu0[j]),
                                  a1 * bf2f((unsigned short)pu1[j])));
      } else {
        v = pu0;
      }
    }
    *(s16x8*)&As[am * 40 + akk] = v;
    #pragma unroll
    for (int i = 0; i < 4; ++i) {
      int ch = tid + i * 256;
      int m = ch >> 2, kk = (ch & 3) * 8;
      *(s16x8*)&Bs[m * 40 + kk] = pb[i];
    }
  };

  loadA(0); loadB(0); storeLDS(0);
  __syncthreads();
  for (int k0 = 0; k0 < 512; k0 += 32) {
    int kn = k0 + 32;
    if (kn < 512) { loadA(kn); loadB(kn); }
    s16x8 af[4], bf[4];
    #pragma unroll
    for (int r = 0; r < 4; ++r)
      af[r] = *(const s16x8*)&As[(r * 16 + m16) * 40 + quad * 8];
    #pragma unroll
    for (int c = 0; c < 4; ++c)
      bf[c] = *(const s16x8*)&Bs[(w * 64 + c * 16 + m16) * 40 + quad * 8];
    #pragma unroll
    for (int r = 0; r < 4; ++r)
      #pragma unroll
      for (int c = 0; c < 4; ++c)
        acc[r][c] = __builtin_amdgcn_mfma_f32_16x16x32_bf16(af[r], bf[c], acc[r][c], 0, 0, 0);
    __syncthreads();
    if (kn < 512) {
      storeLDS(kn);
      __syncthreads();
    }
  }
  const float* __restrict__ bias = g.bias[z];
  float* __restrict__ out = g.out[z];
  #pragma unroll
  for (int r = 0; r < 4; ++r)
    #pragma unroll
    for (int i = 0; i < 4; ++i) {
      int row = row0 + r * 16 + quad * 4 + i;
      if (row < M) {
        #pragma unroll
        for (int c = 0; c < 4; ++c) {
          int col = w * 64 + c * 16 + m16;
          out[(size_t)row * 256 + col] = acc[r][c][i] + bias[col];
        }
      }
    }
}

} // namespace

extern "C" void kernel_launch(void* const* d_in, const int* in_sizes, int n_in,
                              void* d_out, int out_size, void* d_ws, size_t ws_size,
                              hipStream_t stream) {
  (void)in_sizes; (void)n_in; (void)out_size; (void)ws_size;
  const float* x[3] = {(const float*)d_in[0], (const float*)d_in[1], (const float*)d_in[2]};

  // ---- workspace layout ----
  char* p = (char*)d_ws;
  unsigned short* projfull = (unsigned short*)p;  p += (size_t)105000 * 256 * 2;
  unsigned short* nbft = (unsigned short*)p;      p += (size_t)70000 * 256 * 2;
  unsigned short* wcatbt = (unsigned short*)p;    p += (size_t)3 * 256 * 512 * 2;
  int* offs = (int*)p;                            p += (size_t)70004 * 4;
  int* counts = (int*)p;                          p += (size_t)70000 * 4;
  int* subcnt = (int*)p;                          p += (size_t)NBUK * 8 * 4;
  int* ovcnt = (int*)p;                           p += 16;
  int* part = (int*)p;                            p += 256;
  float* att_buf = (float*)p;                     p += (size_t)70000 * 4;
  unsigned int* csr_pay = (unsigned int*)p;       p += (size_t)1120000 * 4;
  // aliases into nbft (dead until gather_all):
  unsigned short* wshT = nbft;
  unsigned short* Wcbt = (unsigned short*)((char*)nbft + 393216);
  // record buffers alias projfull (dead until proj_mfma9, which overwrites all rows):
  unsigned long long* rec = (unsigned long long*)projfull;              // 15.7 MB
  unsigned long long* ovbuf = rec + (size_t)NBUK * 8 * RCAP;            // 0.5 MB
  // bf16 copy of x lives in d_out (dead until final_mfma3 writes real output):
  unsigned short* xb = (unsigned short*)d_out;

  const int n_of[3] = {20000, 10000, 5000};
  const int nbt[3][2] = {{1, 2}, {0, 2}, {0, 1}};
  const int ebase[3][2] = {{3, 6}, {9, 12}, {15, 18}};
  const int nE3[3] = {320000, 160000, 80000};
  const size_t out_off[3] = {0, (size_t)20000 * 256, (size_t)30000 * 256};
  const int tstart[3] = {0, 15000, 40000};
  const int selfoff[3] = {70000, 90000, 100000};
  const int nboff[3] = {0, 40000, 60000};
  const int xboff[3] = {0, 20000, 30000};

  // ---- x -> bf16 ----
  cvt_x3<<<dim3(8750), 256, 0, stream>>>(x[0], x[1], x[2], xb);

  // ---- transpose+cvt: 3 wsh, 3 wcat ----
  Tc6 tc;
  for (int t = 0; t < 3; ++t) {
    tc.src[t] = (const float*)d_in[21 + t * 7 + 3];
    tc.dst[t] = wshT + (size_t)t * 256 * 256;
    tc.R[t] = 256;
    tc.src[3 + t] = (const float*)d_in[21 + t * 7 + 5];
    tc.dst[3 + t] = wcatbt + (size_t)t * 256 * 512;
    tc.R[3 + t] = 512;
  }
  transpose_cvt<<<dim3(8, 16, 6), 256, 0, stream>>>(tc);

  // ---- combined weights via MFMA ----
  Comb9 c9;
  for (int t = 0; t < 3; ++t) {
    int wb = 21 + t * 7;
    for (int j = 0; j < 3; ++j) {
      int combo = t * 3 + j;
      c9.A[combo] = wshT + (size_t)t * 256 * 256;
      c9.B[combo] = (const float*)d_in[wb + j];
      c9.C[combo] = Wcbt + (size_t)combo * 256 * 512;
    }
  }
  combine_mfma<<<dim3(4, 2, 9), 256, 0, stream>>>(c9);

  // ---- CSR build (two-level XCD-local counting sort) ----
  Edges6 ep;
  const int cbase[6] = {0, 20000, 40000, 50000, 60000, 65000};
  for (int t = 0; t < 3; ++t)
    for (int r = 0; r < 2; ++r) {
      int rho = t * 2 + r, eb = ebase[t][r];
      ep.src[rho] = (const int*)d_in[eb];
      ep.dst[rho] = (const int*)d_in[eb + 1];
      ep.w[rho] = (const float*)d_in[eb + 2];
      ep.nE[rho] = nE3[t];
      ep.cbase[rho] = cbase[rho];
    }
  // zero counts + subcnt + ovcnt in one memset (contiguous by layout)
  hipMemsetAsync(counts, 0, (size_t)70000 * 4 + (size_t)NBUK * 8 * 4 + 16, stream);
  binscat<<<dim3(1250, 6), 256, 0, stream>>>(ep, counts, subcnt, ovcnt, rec, ovbuf);
  scan1<<<35, 256, 0, stream>>>(counts, offs, part, 70000);
  scan2<<<1, 64, 0, stream>>>(part, 35, offs + 70000);
  scan3<<<274, 256, 0, stream>>>(offs, part, 70000);
  fine_fill<<<NBUK, 256, 0, stream>>>(offs, subcnt, rec, ovcnt, ovbuf, csr_pay);

  // ---- all 9 projections, one launch (128x128 tiles, global_load_lds) ----
  Proj9 pj;
  for (int t = 0; t < 3; ++t) {
    int nb0 = nbt[t][0], nb1 = nbt[t][1];
    int m0 = n_of[nb0];
    pj.A[t * 3 + 0] = xb + (size_t)xboff[nb0] * 512;
    pj.C[t * 3 + 0] = projfull + (size_t)tstart[t] * 256;
    pj.M[t * 3 + 0] = m0;
    pj.A[t * 3 + 1] = xb + (size_t)xboff[nb1] * 512;
    pj.C[t * 3 + 1] = projfull + (size_t)(tstart[t] + m0) * 256;
    pj.M[t * 3 + 1] = n_of[nb1];
    pj.A[t * 3 + 2] = xb + (size_t)xboff[t] * 512;
    pj.C[t * 3 + 2] = projfull + (size_t)selfoff[t] * 256;
    pj.M[t * 3 + 2] = n_of[t];
    for (int j = 0; j < 3; ++j)
      pj.Bt[t * 3 + j] = Wcbt + (size_t)(t * 3 + j) * 256 * 512;
  }
  proj_mfma9<<<dim3(2, 157, 9), 256, 0, stream>>>(pj);

  // ---- all 6 gathers, one launch ----
  Gather6 gt;
  for (int t = 0; t < 3; ++t) {
    int m0 = n_of[nbt[t][0]];
    for (int r = 0; r < 2; ++r) {
      int rho = t * 2 + r;
      gt.proj[rho] = projfull + (size_t)(tstart[t] + (r ? m0 : 0)) * 256;
      gt.out[rho] = nbft + (size_t)(nboff[t] + r * n_of[t]) * 256;
      gt.cb[rho] = cbase[rho];
      gt.n[rho] = n_of[t];
    }
  }
  gather_all<<<dim3(5000, 6), 256, 0, stream>>>(gt, offs, csr_pay);

  // ---- attention (3 types) ----
  Att3 at;
  for (int t = 0; t < 3; ++t) {
    at.nb[t] = nbft + (size_t)nboff[t] * 256;
    at.self[t] = projfull + (size_t)selfoff[t] * 256;
    at.watt[t] = (const float*)d_in[21 + t * 7 + 4];
    at.att[t] = att_buf + nboff[t];
    at.n[t] = n_of[t];
  }
  e_att3<<<dim3(10000, 1, 3), 256, 0, stream>>>(at);

  // ---- final GEMM (3 types, BM=64, 64x64 wave tiles) ----
  Fin3 fn;
  for (int t = 0; t < 3; ++t) {
    fn.nb[t] = nbft + (size_t)nboff[t] * 256;
    fn.self[t] = projfull + (size_t)selfoff[t] * 256;
    fn.att[t] = att_buf + nboff[t];
    fn.Wt[t] = wcatbt + (size_t)t * 256 * 512;
    fn.bias[t] = (const float*)d_in[21 + t * 7 + 6];
    fn.out[t] = (float*)d_out + out_off[t];
    fn.M[t] = n_of[t];
  }
  final_mfma3<<<dim3(1, 313, 3), 256, 0, stream>>>(fn);
}

// Round 5
// 445.554 us; speedup vs baseline: 1.2283x; 1.2283x over previous
//
#include <hip/hip_runtime.h>

namespace {

typedef short s16x8 __attribute__((ext_vector_type(8)));
typedef float f32x4 __attribute__((ext_vector_type(4)));

__device__ __forceinline__ float bf2f(unsigned short u) {
  return __uint_as_float(((unsigned)u) << 16);
}
__device__ __forceinline__ unsigned short f2bf(float f) {
  unsigned u = __float_as_uint(f);
  u += 0x7fffu + ((u >> 16) & 1u);
  return (unsigned short)(u >> 16);
}

// async global->LDS, 16B per lane. LDS dest is wave-uniform base + lane*16.
typedef __attribute__((address_space(3))) unsigned int lds_u32;
typedef __attribute__((address_space(1))) const unsigned int glob_u32;
__device__ __forceinline__ void gl16(const void* g, void* l) {
  __builtin_amdgcn_global_load_lds((glob_u32*)g, (lds_u32*)l, 16, 0, 0);
}

// x (fp32) -> xb (bf16), 35000x512 total; xb lives in d_out (dead until final_mfma3).
__global__ __launch_bounds__(256) void cvt_x3(const float* __restrict__ x0,
                                              const float* __restrict__ x1,
                                              const float* __restrict__ x2,
                                              unsigned short* __restrict__ out) {
  size_t i = ((size_t)blockIdx.x * 256 + threadIdx.x) * 8;
  const float* src;
  size_t off;
  if (i < (size_t)20000 * 512) { src = x0; off = i; }
  else if (i < (size_t)30000 * 512) { src = x1; off = i - (size_t)20000 * 512; }
  else { src = x2; off = i - (size_t)30000 * 512; }
  float4 a = *(const float4*)(src + off);
  float4 b = *(const float4*)(src + off + 4);
  s16x8 v;
  v[0] = (short)f2bf(a.x); v[1] = (short)f2bf(a.y);
  v[2] = (short)f2bf(a.z); v[3] = (short)f2bf(a.w);
  v[4] = (short)f2bf(b.x); v[5] = (short)f2bf(b.y);
  v[6] = (short)f2bf(b.z); v[7] = (short)f2bf(b.w);
  *(s16x8*)(out + i) = v;
}

// fp32 [R][256] -> bf16 [256][R] (transposed). wsh: R=256, wcat: R=512.
struct Tc6 { const float* src[6]; unsigned short* dst[6]; int R[6]; };
__global__ __launch_bounds__(256) void transpose_cvt(Tc6 a) {
  int mat = blockIdx.z;
  int R = a.R[mat];
  int r0 = blockIdx.y * 32, c0 = blockIdx.x * 32;
  if (r0 >= R) return;
  const float* __restrict__ src = a.src[mat];
  unsigned short* __restrict__ dst = a.dst[mat];
  __shared__ float T[32][33];
  int tx = threadIdx.x & 31, ty = threadIdx.x >> 5;
  #pragma unroll
  for (int j = 0; j < 4; ++j) {
    int r = ty + j * 8;
    T[r][tx] = src[(size_t)(r0 + r) * 256 + c0 + tx];
  }
  __syncthreads();
  #pragma unroll
  for (int j = 0; j < 4; ++j) {
    int c = ty + j * 8;
    dst[(size_t)(c0 + c) * R + r0 + tx] = f2bf(T[tx][c]);
  }
}

// Wcbt[256x512] = wshT[256x256](bf16) @ W[512x256]^T(fp32, cvt on load)
struct Comb9 { const unsigned short* A[9]; const float* B[9]; unsigned short* C[9]; };
__global__ __launch_bounds__(256) void combine_mfma(Comb9 g) {
  int z = blockIdx.z;
  const unsigned short* __restrict__ A = g.A[z];
  const float* __restrict__ B = g.B[z];
  unsigned short* __restrict__ C = g.C[z];
  int row0 = blockIdx.y * 128;
  int col0 = blockIdx.x * 128;
  __shared__ unsigned short As[128 * 40];
  __shared__ unsigned short Bs[128 * 40];
  int tid = threadIdx.x, lane = tid & 63, w = tid >> 6;
  int quad = lane >> 4, m16 = lane & 15;
  f32x4 acc[2][8];
  #pragma unroll
  for (int r = 0; r < 2; ++r)
    #pragma unroll
    for (int c = 0; c < 8; ++c) acc[r][c] = (f32x4){0.f, 0.f, 0.f, 0.f};
  for (int k0 = 0; k0 < 256; k0 += 32) {
    #pragma unroll
    for (int i = 0; i < 2; ++i) {
      int ch = tid + i * 256;
      int m = ch >> 2, kk = (ch & 3) * 8;
      *(s16x8*)&As[m * 40 + kk] = *(const s16x8*)(A + (size_t)(row0 + m) * 256 + k0 + kk);
      const float4* bp = (const float4*)(B + (size_t)(col0 + m) * 256 + k0 + kk);
      float4 b0 = bp[0], b1 = bp[1];
      s16x8 bv;
      bv[0] = (short)f2bf(b0.x); bv[1] = (short)f2bf(b0.y);
      bv[2] = (short)f2bf(b0.z); bv[3] = (short)f2bf(b0.w);
      bv[4] = (short)f2bf(b1.x); bv[5] = (short)f2bf(b1.y);
      bv[6] = (short)f2bf(b1.z); bv[7] = (short)f2bf(b1.w);
      *(s16x8*)&Bs[m * 40 + kk] = bv;
    }
    __syncthreads();
    s16x8 af[2], bf[8];
    #pragma unroll
    for (int r = 0; r < 2; ++r)
      af[r] = *(const s16x8*)&As[(w * 32 + r * 16 + m16) * 40 + quad * 8];
    #pragma unroll
    for (int c = 0; c < 8; ++c)
      bf[c] = *(const s16x8*)&Bs[(c * 16 + m16) * 40 + quad * 8];
    #pragma unroll
    for (int r = 0; r < 2; ++r)
      #pragma unroll
      for (int c = 0; c < 8; ++c)
        acc[r][c] = __builtin_amdgcn_mfma_f32_16x16x32_bf16(af[r], bf[c], acc[r][c], 0, 0, 0);
    __syncthreads();
  }
  #pragma unroll
  for (int r = 0; r < 2; ++r)
    #pragma unroll
    for (int i = 0; i < 4; ++i) {
      int row = row0 + w * 32 + r * 16 + quad * 4 + i;
      #pragma unroll
      for (int c = 0; c < 8; ++c)
        C[(size_t)row * 512 + col0 + c * 16 + m16] = f2bf(acc[r][c][i]);
    }
}

// 9 projections, one launch. m97 structure: 128x128 tile, BK=32, 4 waves x 64x64,
// single-buffered linear LDS, global_load_lds width-16 for both A (bf16) and B (bf16).
struct Proj9 { const unsigned short* A[9]; const unsigned short* Bt[9]; unsigned short* C[9]; int M[9]; };
__global__ __launch_bounds__(256) void proj_mfma9(Proj9 g) {
  int z = blockIdx.z;
  int M = g.M[z];
  int row0 = blockIdx.y * 128;
  if (row0 >= M) return;
  int col0 = blockIdx.x * 128;
  const unsigned short* __restrict__ A = g.A[z];
  const unsigned short* __restrict__ Bt = g.Bt[z];
  unsigned short* __restrict__ C = g.C[z];
  __shared__ unsigned short As[128 * 32];
  __shared__ unsigned short Bs[128 * 32];
  int tid = threadIdx.x, lane = tid & 63, w = tid >> 6;
  int quad = lane >> 4, m16 = lane & 15;
  int lr = lane >> 2, lk = (lane & 3) * 8;
  int r0g = row0 + w * 32 + lr;
  int r1g = r0g + 16;
  const unsigned short* a0p = A + (size_t)(r0g < M ? r0g : M - 1) * 512 + lk;
  const unsigned short* a1p = A + (size_t)(r1g < M ? r1g : M - 1) * 512 + lk;
  const unsigned short* b0p = Bt + (size_t)(col0 + w * 32 + lr) * 512 + lk;
  const unsigned short* b1p = b0p + (size_t)16 * 512;
  unsigned short* as0 = &As[w * 1024];
  unsigned short* as1 = &As[w * 1024 + 512];
  unsigned short* bs0 = &Bs[w * 1024];
  unsigned short* bs1 = &Bs[w * 1024 + 512];
  int wr = (w & 1) * 64, wc = (w >> 1) * 64;
  f32x4 acc[4][4];
  #pragma unroll
  for (int r = 0; r < 4; ++r)
    #pragma unroll
    for (int c = 0; c < 4; ++c) acc[r][c] = (f32x4){0.f, 0.f, 0.f, 0.f};
  for (int k0 = 0; k0 < 512; k0 += 32) {
    gl16(a0p + k0, as0);
    gl16(a1p + k0, as1);
    gl16(b0p + k0, bs0);
    gl16(b1p + k0, bs1);
    __syncthreads();
    s16x8 af[4], bf[4];
    #pragma unroll
    for (int r = 0; r < 4; ++r)
      af[r] = *(const s16x8*)&As[(wr + r * 16 + m16) * 32 + quad * 8];
    #pragma unroll
    for (int c = 0; c < 4; ++c)
      bf[c] = *(const s16x8*)&Bs[(wc + c * 16 + m16) * 32 + quad * 8];
    #pragma unroll
    for (int r = 0; r < 4; ++r)
      #pragma unroll
      for (int c = 0; c < 4; ++c)
        acc[r][c] = __builtin_amdgcn_mfma_f32_16x16x32_bf16(af[r], bf[c], acc[r][c], 0, 0, 0);
    __syncthreads();
  }
  #pragma unroll
  for (int r = 0; r < 4; ++r)
    #pragma unroll
    for (int i = 0; i < 4; ++i) {
      int row = row0 + wr + r * 16 + quad * 4 + i;
      if (row < M) {
        #pragma unroll
        for (int c = 0; c < 4; ++c)
          C[(size_t)row * 256 + col0 + wc + c * 16 + m16] = f2bf(acc[r][c][i]);
      }
    }
}

struct Edges6 { const int* src[6]; const int* dst[6]; const float* w[6]; int nE[6]; int cbase[6]; };

// ---- CSR build: LDS-staged two-level counting sort (no dispatch-order assumptions) ----
// Level 1 (bin1): per 4096-edge chunk, histogram into 137 coarse buckets (512 dsts)
// in LDS, prefix-sum, stage records bucket-sorted in LDS, reserve a global range
// per bucket via one atomic, then write COALESCED bursts (dense in space+time ->
// no 64B-line-per-record write amplification). Fuses the fine per-dst histogram.
// Level 2 (fine2): one block per bucket; LDS per-dst cursors; final 4B payloads
// land in the bucket's contiguous csr_pay window (single block -> single XCD).
// All computed store indices carry defensive clamps (provably unreachable).
#define BSH 9
#define NB2 137            // ceil(70000 / 512)
#define CAP2 10240         // bucket mean 8192, std ~90 -> >20 sigma + overflow path
#define NOV 65536
#define CH 4096
#define NPAY 1120000

__global__ __launch_bounds__(256) void bin1(Edges6 ep, int* __restrict__ counts,
                                            int* __restrict__ bcur, int* __restrict__ ovcnt,
                                            unsigned long long* __restrict__ rec2,
                                            unsigned long long* __restrict__ ovbuf) {
  int rho = blockIdx.y;
  int nE = ep.nE[rho];
  int chunk = blockIdx.x * CH;
  if (chunk >= nE) return;
  int n = nE - chunk; if (n > CH) n = CH;
  const int* __restrict__ srcp = ep.src[rho];
  const int* __restrict__ dstp = ep.dst[rho];
  const float* __restrict__ wp = ep.w[rho];
  int cb = ep.cbase[rho];
  __shared__ int h[256], excl[256], lcur[256], gbase[256];
  __shared__ unsigned long long stage[CH];
  int t = threadIdx.x;
  h[t] = 0;
  gbase[t] = 0;
  __syncthreads();
  int gd[16]; unsigned pv[16];
  #pragma unroll
  for (int j = 0; j < 16; ++j) {
    int idx = t + j * 256;
    gd[j] = -1;
    if (idx < n) {
      int e = chunk + idx;
      int d = dstp[e];
      int g = cb + d;
      if (g < 0) g = 0;
      if (g > 69999) g = 69999;       // defensive (inputs guarantee in-range)
      gd[j] = g;
      pv[j] = (((unsigned)f2bf(wp[e])) << 16) | ((unsigned)srcp[e] & 0x7fffu);
      atomicAdd(&counts[g], 1);
      atomicAdd(&h[g >> BSH], 1);
    }
  }
  __syncthreads();
  // exclusive prefix over h[0..255] (Hillis-Steele)
  int hv = h[t];
  excl[t] = hv;
  __syncthreads();
  for (int off = 1; off < 256; off <<= 1) {
    int v = (t >= off) ? excl[t - off] : 0;
    __syncthreads();
    excl[t] += v;
    __syncthreads();
  }
  int ex = excl[t] - hv;
  __syncthreads();
  excl[t] = ex;
  lcur[t] = ex;
  if (t < NB2 && hv > 0) gbase[t] = atomicAdd(&bcur[t], hv);
  __syncthreads();
  // stage records bucket-sorted in LDS
  #pragma unroll
  for (int j = 0; j < 16; ++j) {
    if (gd[j] >= 0) {
      int b = gd[j] >> BSH;
      int slot = atomicAdd(&lcur[b], 1);
      if (slot >= 0 && slot < CH)     // defensive (sum of h == n <= CH)
        stage[slot] = ((unsigned long long)(unsigned)gd[j] << 32) | pv[j];
    }
  }
  __syncthreads();
  // coalesced burst write-out
  for (int s = t; s < n; s += 256) {
    int lo = 0, hi = NB2 - 1;
    while (lo < hi) {
      int mid = (lo + hi + 1) >> 1;
      if (excl[mid] <= s) lo = mid; else hi = mid - 1;
    }
    int b = lo;
    int gp = gbase[b] + (s - excl[b]);
    if (gp >= 0 && gp < CAP2) rec2[(size_t)b * CAP2 + gp] = stage[s];
    else { int op = atomicAdd(ovcnt, 1); ovbuf[op & (NOV - 1)] = stage[s]; }
  }
}

__global__ __launch_bounds__(256) void scan1(const int* __restrict__ cnt, int* __restrict__ out,
                                             int* __restrict__ part, int len) {
  __shared__ int sh[256];
  int base = blockIdx.x * 2048 + threadIdx.x * 8;
  int v[8];
  int s = 0;
  #pragma unroll
  for (int j = 0; j < 8; ++j) {
    int i = base + j;
    int x = (i < len) ? cnt[i] : 0;
    v[j] = s;
    s += x;
  }
  sh[threadIdx.x] = s;
  __syncthreads();
  for (int off = 1; off < 256; off <<= 1) {
    int t = (threadIdx.x >= off) ? sh[threadIdx.x - off] : 0;
    __syncthreads();
    sh[threadIdx.x] += t;
    __syncthreads();
  }
  int texcl = sh[threadIdx.x] - s;
  #pragma unroll
  for (int j = 0; j < 8; ++j) {
    int i = base + j;
    if (i < len) out[i] = texcl + v[j];
  }
  if (threadIdx.x == 255) part[blockIdx.x] = sh[255];
}

__global__ void scan2(int* __restrict__ part, int nb, int* __restrict__ total_out) {
  __shared__ int sh[64];
  int t = threadIdx.x;
  int v = (t < nb) ? part[t] : 0;
  sh[t] = v;
  __syncthreads();
  for (int off = 1; off < 64; off <<= 1) {
    int x = (t >= off) ? sh[t - off] : 0;
    __syncthreads();
    sh[t] += x;
    __syncthreads();
  }
  if (t < nb) part[t] = sh[t] - v;
  if (t == 63) *total_out = sh[63];
}

__global__ __launch_bounds__(256) void scan3(int* __restrict__ offs,
                                             const int* __restrict__ part, int len) {
  int i = blockIdx.x * 256 + threadIdx.x;
  if (i >= len) return;
  offs[i] += part[i >> 11];
}

__global__ __launch_bounds__(512) void fine2(const int* __restrict__ offs,
                                             const int* __restrict__ bcur,
                                             const unsigned long long* __restrict__ rec2,
                                             const int* __restrict__ ovcnt,
                                             const unsigned long long* __restrict__ ovbuf,
                                             unsigned int* __restrict__ pay) {
  int b = blockIdx.x;
  __shared__ int cur[512];
  int t = threadIdx.x;
  {
    int gd = (b << BSH) + t;
    cur[t] = (gd < 70000) ? offs[gd] : 0;
  }
  __syncthreads();
  int nrec = bcur[b];
  nrec = nrec < CAP2 ? nrec : CAP2;
  const unsigned long long* rp = rec2 + (size_t)b * CAP2;
  for (int i = t; i < nrec; i += 512) {
    unsigned long long r = rp[i];
    int ld = (int)(r >> 32) & 511;
    int pos = atomicAdd(&cur[ld], 1);
    if (pos >= 0 && pos < NPAY) pay[pos] = (unsigned)r;  // defensive
  }
  int ovn = *ovcnt;
  ovn = ovn < NOV ? ovn : NOV;
  for (int i = t; i < ovn; i += 512) {
    unsigned long long r = ovbuf[i];
    int gd = (int)(r >> 32);
    if ((gd >> BSH) == b) {
      int pos = atomicAdd(&cur[gd & 511], 1);
      if (pos >= 0 && pos < NPAY) pay[pos] = (unsigned)r;
    }
  }
}

// all 6 relations; one wave per (dst, rel); 4 edges in flight (2 per half-wave)
struct Gather6 { const unsigned short* proj[6]; unsigned short* out[6]; int cb[6]; int n[6]; };
__global__ __launch_bounds__(256) void gather_all(Gather6 g, const int* __restrict__ offs,
                                                  const unsigned int* __restrict__ pay) {
  int rho = blockIdx.y;
  int n = g.n[rho];
  int d = blockIdx.x * 4 + (threadIdx.x >> 6);
  if (d >= n) return;
  int lane = threadIdx.x & 63, half = lane >> 5, l32 = lane & 31;
  const unsigned short* __restrict__ proj = g.proj[rho];
  const int* of = offs + g.cb[rho];
  int s0 = of[d], s1 = of[d + 1];
  float acc[8] = {};
  int e = s0 + half;
  for (; e + 2 < s1; e += 4) {
    unsigned int u0 = pay[e], u1 = pay[e + 2];
    float wt0 = bf2f((unsigned short)(u0 >> 16));
    float wt1 = bf2f((unsigned short)(u1 >> 16));
    s16x8 v0 = *(const s16x8*)(proj + (size_t)(u0 & 0xffffu) * 256 + l32 * 8);
    s16x8 v1 = *(const s16x8*)(proj + (size_t)(u1 & 0xffffu) * 256 + l32 * 8);
    #pragma unroll
    for (int j = 0; j < 8; ++j) {
      acc[j] = fmaf(bf2f((unsigned short)v0[j]), wt0, acc[j]);
      acc[j] = fmaf(bf2f((unsigned short)v1[j]), wt1, acc[j]);
    }
  }
  if (e < s1) {
    unsigned int u = pay[e];
    float wt = bf2f((unsigned short)(u >> 16));
    s16x8 v = *(const s16x8*)(proj + (size_t)(u & 0xffffu) * 256 + l32 * 8);
    #pragma unroll
    for (int j = 0; j < 8; ++j) acc[j] = fmaf(bf2f((unsigned short)v[j]), wt, acc[j]);
  }
  #pragma unroll
  for (int j = 0; j < 8; ++j) acc[j] += __shfl(acc[j], lane ^ 32, 64);
  if (half == 0) {
    s16x8 o;
    #pragma unroll
    for (int j = 0; j < 8; ++j) o[j] = (short)f2bf(acc[j]);
    *(s16x8*)(g.out[rho] + (size_t)d * 256 + l32 * 8) = o;
  }
}

// all 3 types: scores + FAITHFUL reshape(n,2) softmax over adjacent e-pairs
struct Att3 { const unsigned short* nb[3]; const unsigned short* self[3];
              const float* watt[3]; float* att[3]; int n[3]; };
__global__ __launch_bounds__(256) void e_att3(Att3 g) {
  int z = blockIdx.z;
  int n = g.n[z];
  int wv = threadIdx.x >> 6;
  int idx = blockIdx.x * 4 + wv;
  int lane = threadIdx.x & 63;
  __shared__ float ev[4];
  float sum = 0.f;
  if (idx < 2 * n) {
    int i = idx < n ? idx : idx - n;
    ushort4 v  = *(const ushort4*)(g.nb[z] + (size_t)idx * 256 + (lane << 2));
    ushort4 sv = *(const ushort4*)(g.self[z] + (size_t)i * 256 + (lane << 2));
    float4 wa = *(const float4*)(g.watt[z] + (lane << 2));
    float4 wb = *(const float4*)(g.watt[z] + 256 + (lane << 2));
    sum = bf2f(v.x) * wa.x + bf2f(v.y) * wa.y + bf2f(v.z) * wa.z + bf2f(v.w) * wa.w +
          bf2f(sv.x) * wb.x + bf2f(sv.y) * wb.y + bf2f(sv.z) * wb.z + bf2f(sv.w) * wb.w;
    #pragma unroll
    for (int off = 32; off > 0; off >>= 1) sum += __shfl_down(sum, off, 64);
  }
  if (lane == 0) ev[wv] = sum;
  __syncthreads();
  if (threadIdx.x < 2) {
    int base = blockIdx.x * 4 + threadIdx.x * 2;
    if (base < 2 * n) {
      float f0 = ev[threadIdx.x * 2], f1 = ev[threadIdx.x * 2 + 1];
      f0 = f0 > 0.f ? f0 : 0.01f * f0;
      f1 = f1 > 0.f ? f1 : 0.01f * f1;
      float m = fmaxf(f0, f1);
      float a = expf(f0 - m), b = expf(f1 - m);
      float inv = 1.f / (a + b);
      g.att[z][base] = a * inv;
      g.att[z][base + 1] = b * inv;
    }
  }
}

// all 3 types, BM=64/BN=256, 64x64 wave tiles, pipelined staging.
struct Fin3 { const unsigned short* nb[3]; const unsigned short* self[3]; const float* att[3];
              const unsigned short* Wt[3]; const float* bias[3]; float* out[3]; int M[3]; };
__global__ __launch_bounds__(256, 3) void final_mfma3(Fin3 g) {
  int z = blockIdx.z;
  int M = g.M[z];
  int row0 = blockIdx.y * 64;
  if (row0 >= M) return;
  const unsigned short* __restrict__ nbft = g.nb[z];
  const unsigned short* __restrict__ selfb = g.self[z];
  const float* __restrict__ att = g.att[z];
  const unsigned short* __restrict__ Wt = g.Wt[z];
  __shared__ unsigned short As[64 * 40];
  __shared__ unsigned short Bs[256 * 40];
  int tid = threadIdx.x, lane = tid & 63, w = tid >> 6;
  int quad = lane >> 4, m16 = lane & 15;
  int am = tid >> 2, akk = (tid & 3) * 8;
  int gr = row0 + am;
  float a0 = 0.f, a1 = 0.f;
  if (gr < M) { a0 = att[2 * gr]; a1 = att[2 * gr + 1]; }
  f32x4 acc[4][4];
  #pragma unroll
  for (int r = 0; r < 4; ++r)
    #pragma unroll
    for (int c = 0; c < 4; ++c) acc[r][c] = (f32x4){0.f, 0.f, 0.f, 0.f};

  s16x8 pu0 = {}, pu1 = {};
  s16x8 pb[4];

  auto loadA = [&](int k0) {
    int kg = k0 + akk;
    if (gr < M) {
      if (kg < 256) {
        pu0 = *(const s16x8*)(nbft + (size_t)gr * 256 + kg);
        pu1 = *(const s16x8*)(nbft + ((size_t)M + gr) * 256 + kg);
      } else {
        pu0 = *(const s16x8*)(selfb + (size_t)gr * 256 + (kg - 256));
      }
    }
  };
  auto loadB = [&](int k0) {
    #pragma unroll
    for (int i = 0; i < 4; ++i) {
      int ch = tid + i * 256;
      int m = ch >> 2, kk = (ch & 3) * 8;
      pb[i] = *(const s16x8*)(Wt + (size_t)m * 512 + k0 + kk);
    }
  };
  auto storeLDS = [&](int k0) {
    int kg = k0 + akk;
    s16x8 v = {};
    if (gr < M) {
      if (kg < 256) {
        #pragma unroll
        for (int j = 0; j < 8; ++j)
          v[j] = (short)f2bf(fmaf(a0, bf2f((unsigned short)pu0[j]),
                                  a1 * bf2f((unsigned short)pu1[j])));
      } else {
        v = pu0;
      }
    }
    *(s16x8*)&As[am * 40 + akk] = v;
    #pragma unroll
    for (int i = 0; i < 4; ++i) {
      int ch = tid + i * 256;
      int m = ch >> 2, kk = (ch & 3) * 8;
      *(s16x8*)&Bs[m * 40 + kk] = pb[i];
    }
  };

  loadA(0); loadB(0); storeLDS(0);
  __syncthreads();
  for (int k0 = 0; k0 < 512; k0 += 32) {
    int kn = k0 + 32;
    if (kn < 512) { loadA(kn); loadB(kn); }
    s16x8 af[4], bf[4];
    #pragma unroll
    for (int r = 0; r < 4; ++r)
      af[r] = *(const s16x8*)&As[(r * 16 + m16) * 40 + quad * 8];
    #pragma unroll
    for (int c = 0; c < 4; ++c)
      bf[c] = *(const s16x8*)&Bs[(w * 64 + c * 16 + m16) * 40 + quad * 8];
    #pragma unroll
    for (int r = 0; r < 4; ++r)
      #pragma unroll
      for (int c = 0; c < 4; ++c)
        acc[r][c] = __builtin_amdgcn_mfma_f32_16x16x32_bf16(af[r], bf[c], acc[r][c], 0, 0, 0);
    __syncthreads();
    if (kn < 512) {
      storeLDS(kn);
      __syncthreads();
    }
  }
  const float* __restrict__ bias = g.bias[z];
  float* __restrict__ out = g.out[z];
  #pragma unroll
  for (int r = 0; r < 4; ++r)
    #pragma unroll
    for (int i = 0; i < 4; ++i) {
      int row = row0 + r * 16 + quad * 4 + i;
      if (row < M) {
        #pragma unroll
        for (int c = 0; c < 4; ++c) {
          int col = w * 64 + c * 16 + m16;
          out[(size_t)row * 256 + col] = acc[r][c][i] + bias[col];
        }
      }
    }
}

} // namespace

extern "C" void kernel_launch(void* const* d_in, const int* in_sizes, int n_in,
                              void* d_out, int out_size, void* d_ws, size_t ws_size,
                              hipStream_t stream) {
  (void)in_sizes; (void)n_in; (void)out_size; (void)ws_size;
  const float* x[3] = {(const float*)d_in[0], (const float*)d_in[1], (const float*)d_in[2]};

  // ---- workspace layout ----
  char* p = (char*)d_ws;
  unsigned short* projfull = (unsigned short*)p;  p += (size_t)105000 * 256 * 2;
  unsigned short* nbft = (unsigned short*)p;      p += (size_t)70000 * 256 * 2;
  unsigned short* wcatbt = (unsigned short*)p;    p += (size_t)3 * 256 * 512 * 2;
  int* offs = (int*)p;                            p += (size_t)70004 * 4;
  int* counts = (int*)p;                          p += (size_t)70000 * 4;   // zeroed
  int* bcur = (int*)p;                            p += 160 * 4;             // zeroed
  int* ovcnt = (int*)p;                           p += 16;                  // zeroed
  int* part = (int*)p;                            p += 256;
  float* att_buf = (float*)p;                     p += (size_t)70000 * 4;
  unsigned int* csr_pay = (unsigned int*)p;       p += (size_t)1120000 * 4;
  // aliases into nbft (dead until gather_all):
  unsigned short* wshT = nbft;
  unsigned short* Wcbt = (unsigned short*)((char*)nbft + 393216);
  // record buffers alias projfull (dead until proj_mfma9 overwrites all rows):
  unsigned long long* rec2 = (unsigned long long*)projfull;            // 11.2 MB
  unsigned long long* ovbuf = rec2 + (size_t)NB2 * CAP2;               // 0.5 MB
  // bf16 copy of x lives in d_out (dead until final_mfma3 writes real output):
  unsigned short* xb = (unsigned short*)d_out;

  const int n_of[3] = {20000, 10000, 5000};
  const int nbt[3][2] = {{1, 2}, {0, 2}, {0, 1}};
  const int ebase[3][2] = {{3, 6}, {9, 12}, {15, 18}};
  const int nE3[3] = {320000, 160000, 80000};
  const size_t out_off[3] = {0, (size_t)20000 * 256, (size_t)30000 * 256};
  const int tstart[3] = {0, 15000, 40000};
  const int selfoff[3] = {70000, 90000, 100000};
  const int nboff[3] = {0, 40000, 60000};
  const int xboff[3] = {0, 20000, 30000};

  // ---- x -> bf16 ----
  cvt_x3<<<dim3(8750), 256, 0, stream>>>(x[0], x[1], x[2], xb);

  // ---- transpose+cvt: 3 wsh, 3 wcat ----
  Tc6 tc;
  for (int t = 0; t < 3; ++t) {
    tc.src[t] = (const float*)d_in[21 + t * 7 + 3];
    tc.dst[t] = wshT + (size_t)t * 256 * 256;
    tc.R[t] = 256;
    tc.src[3 + t] = (const float*)d_in[21 + t * 7 + 5];
    tc.dst[3 + t] = wcatbt + (size_t)t * 256 * 512;
    tc.R[3 + t] = 512;
  }
  transpose_cvt<<<dim3(8, 16, 6), 256, 0, stream>>>(tc);

  // ---- combined weights via MFMA ----
  Comb9 c9;
  for (int t = 0; t < 3; ++t) {
    int wb = 21 + t * 7;
    for (int j = 0; j < 3; ++j) {
      int combo = t * 3 + j;
      c9.A[combo] = wshT + (size_t)t * 256 * 256;
      c9.B[combo] = (const float*)d_in[wb + j];
      c9.C[combo] = Wcbt + (size_t)combo * 256 * 512;
    }
  }
  combine_mfma<<<dim3(4, 2, 9), 256, 0, stream>>>(c9);

  // ---- CSR build (LDS-staged two-level counting sort) ----
  Edges6 ep;
  const int cbase[6] = {0, 20000, 40000, 50000, 60000, 65000};
  for (int t = 0; t < 3; ++t)
    for (int r = 0; r < 2; ++r) {
      int rho = t * 2 + r, eb = ebase[t][r];
      ep.src[rho] = (const int*)d_in[eb];
      ep.dst[rho] = (const int*)d_in[eb + 1];
      ep.w[rho] = (const float*)d_in[eb + 2];
      ep.nE[rho] = nE3[t];
      ep.cbase[rho] = cbase[rho];
    }
  // zero counts + bcur + ovcnt in one memset (contiguous by layout)
  hipMemsetAsync(counts, 0, (size_t)70000 * 4 + 160 * 4 + 16, stream);
  bin1<<<dim3(79, 6), 256, 0, stream>>>(ep, counts, bcur, ovcnt, rec2, ovbuf);
  scan1<<<35, 256, 0, stream>>>(counts, offs, part, 70000);
  scan2<<<1, 64, 0, stream>>>(part, 35, offs + 70000);
  scan3<<<274, 256, 0, stream>>>(offs, part, 70000);
  fine2<<<NB2, 512, 0, stream>>>(offs, bcur, rec2, ovcnt, ovbuf, csr_pay);

  // ---- all 9 projections, one launch (128x128 tiles, global_load_lds) ----
  Proj9 pj;
  for (int t = 0; t < 3; ++t) {
    int nb0 = nbt[t][0], nb1 = nbt[t][1];
    int m0 = n_of[nb0];
    pj.A[t * 3 + 0] = xb + (size_t)xboff[nb0] * 512;
    pj.C[t * 3 + 0] = projfull + (size_t)tstart[t] * 256;
    pj.M[t * 3 + 0] = m0;
    pj.A[t * 3 + 1] = xb + (size_t)xboff[nb1] * 512;
    pj.C[t * 3 + 1] = projfull + (size_t)(tstart[t] + m0) * 256;
    pj.M[t * 3 + 1] = n_of[nb1];
    pj.A[t * 3 + 2] = xb + (size_t)xboff[t] * 512;
    pj.C[t * 3 + 2] = projfull + (size_t)selfoff[t] * 256;
    pj.M[t * 3 + 2] = n_of[t];
    for (int j = 0; j < 3; ++j)
      pj.Bt[t * 3 + j] = Wcbt + (size_t)(t * 3 + j) * 256 * 512;
  }
  proj_mfma9<<<dim3(2, 157, 9), 256, 0, stream>>>(pj);

  // ---- all 6 gathers, one launch ----
  Gather6 gt;
  for (int t = 0; t < 3; ++t) {
    int m0 = n_of[nbt[t][0]];
    for (int r = 0; r < 2; ++r) {
      int rho = t * 2 + r;
      gt.proj[rho] = projfull + (size_t)(tstart[t] + (r ? m0 : 0)) * 256;
      gt.out[rho] = nbft + (size_t)(nboff[t] + r * n_of[t]) * 256;
      gt.cb[rho] = cbase[rho];
      gt.n[rho] = n_of[t];
    }
  }
  gather_all<<<dim3(5000, 6), 256, 0, stream>>>(gt, offs, csr_pay);

  // ---- attention (3 types) ----
  Att3 at;
  for (int t = 0; t < 3; ++t) {
    at.nb[t] = nbft + (size_t)nboff[t] * 256;
    at.self[t] = projfull + (size_t)selfoff[t] * 256;
    at.watt[t] = (const float*)d_in[21 + t * 7 + 4];
    at.att[t] = att_buf + nboff[t];
    at.n[t] = n_of[t];
  }
  e_att3<<<dim3(10000, 1, 3), 256, 0, stream>>>(at);

  // ---- final GEMM (3 types, BM=64, 64x64 wave tiles) ----
  Fin3 fn;
  for (int t = 0; t < 3; ++t) {
    fn.nb[t] = nbft + (size_t)nboff[t] * 256;
    fn.self[t] = projfull + (size_t)selfoff[t] * 256;
    fn.att[t] = att_buf + nboff[t];
    fn.Wt[t] = wcatbt + (size_t)t * 256 * 512;
    fn.bias[t] = (const float*)d_in[21 + t * 7 + 6];
    fn.out[t] = (float*)d_out + out_off[t];
    fn.M[t] = n_of[t];
  }
  final_mfma3<<<dim3(1, 313, 3), 256, 0, stream>>>(fn);
}

// Round 6
// 433.296 us; speedup vs baseline: 1.2630x; 1.0283x over previous
//
#include <hip/hip_runtime.h>

namespace {

typedef short s16x8 __attribute__((ext_vector_type(8)));
typedef float f32x4 __attribute__((ext_vector_type(4)));

__device__ __forceinline__ float bf2f(unsigned short u) {
  return __uint_as_float(((unsigned)u) << 16);
}
__device__ __forceinline__ unsigned short f2bf(float f) {
  unsigned u = __float_as_uint(f);
  u += 0x7fffu + ((u >> 16) & 1u);
  return (unsigned short)(u >> 16);
}

// async global->LDS, 16B per lane. LDS dest is wave-uniform base + lane*16.
typedef __attribute__((address_space(3))) unsigned int lds_u32;
typedef __attribute__((address_space(1))) const unsigned int glob_u32;
__device__ __forceinline__ void gl16(const void* g, void* l) {
  __builtin_amdgcn_global_load_lds((glob_u32*)g, (lds_u32*)l, 16, 0, 0);
}

// x (fp32) -> xb (bf16), 35000x512 total; xb lives in d_out (dead until final_mfma3).
__global__ __launch_bounds__(256) void cvt_x3(const float* __restrict__ x0,
                                              const float* __restrict__ x1,
                                              const float* __restrict__ x2,
                                              unsigned short* __restrict__ out) {
  size_t i = ((size_t)blockIdx.x * 256 + threadIdx.x) * 8;
  const float* src;
  size_t off;
  if (i < (size_t)20000 * 512) { src = x0; off = i; }
  else if (i < (size_t)30000 * 512) { src = x1; off = i - (size_t)20000 * 512; }
  else { src = x2; off = i - (size_t)30000 * 512; }
  float4 a = *(const float4*)(src + off);
  float4 b = *(const float4*)(src + off + 4);
  s16x8 v;
  v[0] = (short)f2bf(a.x); v[1] = (short)f2bf(a.y);
  v[2] = (short)f2bf(a.z); v[3] = (short)f2bf(a.w);
  v[4] = (short)f2bf(b.x); v[5] = (short)f2bf(b.y);
  v[6] = (short)f2bf(b.z); v[7] = (short)f2bf(b.w);
  *(s16x8*)(out + i) = v;
}

// fp32 [R][256] -> bf16 [256][R] (transposed). wsh: R=256, wcat: R=512.
struct Tc6 { const float* src[6]; unsigned short* dst[6]; int R[6]; };
__global__ __launch_bounds__(256) void transpose_cvt(Tc6 a) {
  int mat = blockIdx.z;
  int R = a.R[mat];
  int r0 = blockIdx.y * 32, c0 = blockIdx.x * 32;
  if (r0 >= R) return;
  const float* __restrict__ src = a.src[mat];
  unsigned short* __restrict__ dst = a.dst[mat];
  __shared__ float T[32][33];
  int tx = threadIdx.x & 31, ty = threadIdx.x >> 5;
  #pragma unroll
  for (int j = 0; j < 4; ++j) {
    int r = ty + j * 8;
    T[r][tx] = src[(size_t)(r0 + r) * 256 + c0 + tx];
  }
  __syncthreads();
  #pragma unroll
  for (int j = 0; j < 4; ++j) {
    int c = ty + j * 8;
    dst[(size_t)(c0 + c) * R + r0 + tx] = f2bf(T[tx][c]);
  }
}

// Wcbt[256x512] = wshT[256x256](bf16) @ W[512x256]^T(fp32, cvt on load)
struct Comb9 { const unsigned short* A[9]; const float* B[9]; unsigned short* C[9]; };
__global__ __launch_bounds__(256) void combine_mfma(Comb9 g) {
  int z = blockIdx.z;
  const unsigned short* __restrict__ A = g.A[z];
  const float* __restrict__ B = g.B[z];
  unsigned short* __restrict__ C = g.C[z];
  int row0 = blockIdx.y * 128;
  int col0 = blockIdx.x * 128;
  __shared__ unsigned short As[128 * 40];
  __shared__ unsigned short Bs[128 * 40];
  int tid = threadIdx.x, lane = tid & 63, w = tid >> 6;
  int quad = lane >> 4, m16 = lane & 15;
  f32x4 acc[2][8];
  #pragma unroll
  for (int r = 0; r < 2; ++r)
    #pragma unroll
    for (int c = 0; c < 8; ++c) acc[r][c] = (f32x4){0.f, 0.f, 0.f, 0.f};
  for (int k0 = 0; k0 < 256; k0 += 32) {
    #pragma unroll
    for (int i = 0; i < 2; ++i) {
      int ch = tid + i * 256;
      int m = ch >> 2, kk = (ch & 3) * 8;
      *(s16x8*)&As[m * 40 + kk] = *(const s16x8*)(A + (size_t)(row0 + m) * 256 + k0 + kk);
      const float4* bp = (const float4*)(B + (size_t)(col0 + m) * 256 + k0 + kk);
      float4 b0 = bp[0], b1 = bp[1];
      s16x8 bv;
      bv[0] = (short)f2bf(b0.x); bv[1] = (short)f2bf(b0.y);
      bv[2] = (short)f2bf(b0.z); bv[3] = (short)f2bf(b0.w);
      bv[4] = (short)f2bf(b1.x); bv[5] = (short)f2bf(b1.y);
      bv[6] = (short)f2bf(b1.z); bv[7] = (short)f2bf(b1.w);
      *(s16x8*)&Bs[m * 40 + kk] = bv;
    }
    __syncthreads();
    s16x8 af[2], bf[8];
    #pragma unroll
    for (int r = 0; r < 2; ++r)
      af[r] = *(const s16x8*)&As[(w * 32 + r * 16 + m16) * 40 + quad * 8];
    #pragma unroll
    for (int c = 0; c < 8; ++c)
      bf[c] = *(const s16x8*)&Bs[(c * 16 + m16) * 40 + quad * 8];
    #pragma unroll
    for (int r = 0; r < 2; ++r)
      #pragma unroll
      for (int c = 0; c < 8; ++c)
        acc[r][c] = __builtin_amdgcn_mfma_f32_16x16x32_bf16(af[r], bf[c], acc[r][c], 0, 0, 0);
    __syncthreads();
  }
  #pragma unroll
  for (int r = 0; r < 2; ++r)
    #pragma unroll
    for (int i = 0; i < 4; ++i) {
      int row = row0 + w * 32 + r * 16 + quad * 4 + i;
      #pragma unroll
      for (int c = 0; c < 8; ++c)
        C[(size_t)row * 512 + col0 + c * 16 + m16] = f2bf(acc[r][c][i]);
    }
}

// 9 projections, one launch. m97 structure: 128x128 tile, BK=32, 4 waves x 64x64,
// single-buffered linear LDS, global_load_lds width-16 for both A (bf16) and B (bf16).
struct Proj9 { const unsigned short* A[9]; const unsigned short* Bt[9]; unsigned short* C[9]; int M[9]; };
__global__ __launch_bounds__(256) void proj_mfma9(Proj9 g) {
  int z = blockIdx.z;
  int M = g.M[z];
  int row0 = blockIdx.y * 128;
  if (row0 >= M) return;
  int col0 = blockIdx.x * 128;
  const unsigned short* __restrict__ A = g.A[z];
  const unsigned short* __restrict__ Bt = g.Bt[z];
  unsigned short* __restrict__ C = g.C[z];
  __shared__ unsigned short As[128 * 32];
  __shared__ unsigned short Bs[128 * 32];
  int tid = threadIdx.x, lane = tid & 63, w = tid >> 6;
  int quad = lane >> 4, m16 = lane & 15;
  int lr = lane >> 2, lk = (lane & 3) * 8;
  int r0g = row0 + w * 32 + lr;
  int r1g = r0g + 16;
  const unsigned short* a0p = A + (size_t)(r0g < M ? r0g : M - 1) * 512 + lk;
  const unsigned short* a1p = A + (size_t)(r1g < M ? r1g : M - 1) * 512 + lk;
  const unsigned short* b0p = Bt + (size_t)(col0 + w * 32 + lr) * 512 + lk;
  const unsigned short* b1p = b0p + (size_t)16 * 512;
  unsigned short* as0 = &As[w * 1024];
  unsigned short* as1 = &As[w * 1024 + 512];
  unsigned short* bs0 = &Bs[w * 1024];
  unsigned short* bs1 = &Bs[w * 1024 + 512];
  int wr = (w & 1) * 64, wc = (w >> 1) * 64;
  f32x4 acc[4][4];
  #pragma unroll
  for (int r = 0; r < 4; ++r)
    #pragma unroll
    for (int c = 0; c < 4; ++c) acc[r][c] = (f32x4){0.f, 0.f, 0.f, 0.f};
  for (int k0 = 0; k0 < 512; k0 += 32) {
    gl16(a0p + k0, as0);
    gl16(a1p + k0, as1);
    gl16(b0p + k0, bs0);
    gl16(b1p + k0, bs1);
    __syncthreads();
    s16x8 af[4], bf[4];
    #pragma unroll
    for (int r = 0; r < 4; ++r)
      af[r] = *(const s16x8*)&As[(wr + r * 16 + m16) * 32 + quad * 8];
    #pragma unroll
    for (int c = 0; c < 4; ++c)
      bf[c] = *(const s16x8*)&Bs[(wc + c * 16 + m16) * 32 + quad * 8];
    #pragma unroll
    for (int r = 0; r < 4; ++r)
      #pragma unroll
      for (int c = 0; c < 4; ++c)
        acc[r][c] = __builtin_amdgcn_mfma_f32_16x16x32_bf16(af[r], bf[c], acc[r][c], 0, 0, 0);
    __syncthreads();
  }
  #pragma unroll
  for (int r = 0; r < 4; ++r)
    #pragma unroll
    for (int i = 0; i < 4; ++i) {
      int row = row0 + wr + r * 16 + quad * 4 + i;
      if (row < M) {
        #pragma unroll
        for (int c = 0; c < 4; ++c)
          C[(size_t)row * 256 + col0 + wc + c * 16 + m16] = f2bf(acc[r][c][i]);
      }
    }
}

struct Edges6 { const int* src[6]; const int* dst[6]; const float* w[6]; int nE[6]; int cbase[6]; };

// ---- CSR build: LDS-staged two-level counting sort (no dispatch-order assumptions) ----
// Level 1 (bin1): per 1024-edge chunk (small chunk -> ~1100 blocks -> occupancy;
// round-5 PMC showed the 4096-chunk version at 9% occupancy, latency-bound),
// histogram into 137 coarse buckets (512 dsts) via LDS, wave-shuffle prefix scan
// (6 shfl steps, 1 barrier vs 16-barrier Hillis-Steele), stage records
// bucket-sorted in LDS, reserve one global range per bucket, write coalesced
// bursts. Fuses the fine per-dst histogram.
// Level 2 (fine2): one block per bucket; LDS per-dst cursors; final 4B payloads
// land in the bucket's contiguous csr_pay window.
#define BSH 9
#define NB2 137            // ceil(70000 / 512)
#define CAP2 10240         // bucket mean 8192, std ~90 -> >20 sigma + overflow path
#define NOV 65536
#define CH 1024
#define NPAY 1120000

__global__ __launch_bounds__(256) void bin1(Edges6 ep, int* __restrict__ counts,
                                            int* __restrict__ bcur, int* __restrict__ ovcnt,
                                            unsigned long long* __restrict__ rec2,
                                            unsigned long long* __restrict__ ovbuf) {
  int rho = blockIdx.y;
  int nE = ep.nE[rho];
  int chunk = blockIdx.x * CH;
  if (chunk >= nE) return;
  int n = nE - chunk; if (n > CH) n = CH;
  const int* __restrict__ srcp = ep.src[rho];
  const int* __restrict__ dstp = ep.dst[rho];
  const float* __restrict__ wp = ep.w[rho];
  int cb = ep.cbase[rho];
  __shared__ int h[256], excl[256], lcur[256], gbase[256];
  __shared__ int wsum[4];
  __shared__ unsigned long long stage[CH];
  int t = threadIdx.x;
  h[t] = 0;
  gbase[t] = 0;
  __syncthreads();
  int gd[4]; unsigned pv[4];
  #pragma unroll
  for (int j = 0; j < 4; ++j) {
    int idx = t + j * 256;
    gd[j] = -1;
    if (idx < n) {
      int e = chunk + idx;
      int g = cb + dstp[e];
      if (g < 0) g = 0;
      if (g > 69999) g = 69999;       // defensive (inputs guarantee in-range)
      gd[j] = g;
      pv[j] = (((unsigned)f2bf(wp[e])) << 16) | ((unsigned)srcp[e] & 0x7fffu);
      atomicAdd(&counts[g], 1);
      atomicAdd(&h[g >> BSH], 1);
    }
  }
  __syncthreads();
  int hv = h[t];
  // wave-shuffle inclusive scan over 256 entries (4 waves x 64 lanes)
  int lane = t & 63, wv = t >> 6;
  int v = hv;
  #pragma unroll
  for (int off = 1; off < 64; off <<= 1) {
    int u = __shfl_up(v, off, 64);
    if (lane >= off) v += u;
  }
  if (lane == 63) wsum[wv] = v;
  __syncthreads();
  int add = 0;
  #pragma unroll
  for (int k = 0; k < 3; ++k)
    if (k < wv) add += wsum[k];
  v += add;
  int ex = v - hv;
  excl[t] = ex;
  lcur[t] = ex;
  if (t < NB2 && hv > 0) gbase[t] = atomicAdd(&bcur[t], hv);
  __syncthreads();
  // stage records bucket-sorted in LDS
  #pragma unroll
  for (int j = 0; j < 4; ++j) {
    if (gd[j] >= 0) {
      int b = gd[j] >> BSH;
      int slot = atomicAdd(&lcur[b], 1);
      if (slot >= 0 && slot < CH)     // defensive (sum of h == n <= CH)
        stage[slot] = ((unsigned long long)(unsigned)gd[j] << 32) | pv[j];
    }
  }
  __syncthreads();
  // coalesced burst write-out
  for (int s = t; s < n; s += 256) {
    int lo = 0, hi = NB2 - 1;
    while (lo < hi) {
      int mid = (lo + hi + 1) >> 1;
      if (excl[mid] <= s) lo = mid; else hi = mid - 1;
    }
    int b = lo;
    int gp = gbase[b] + (s - excl[b]);
    if (gp >= 0 && gp < CAP2) rec2[(size_t)b * CAP2 + gp] = stage[s];
    else { int op = atomicAdd(ovcnt, 1); ovbuf[op & (NOV - 1)] = stage[s]; }
  }
}

__global__ __launch_bounds__(256) void scan1(const int* __restrict__ cnt, int* __restrict__ out,
                                             int* __restrict__ part, int len) {
  __shared__ int sh[256];
  int base = blockIdx.x * 2048 + threadIdx.x * 8;
  int v[8];
  int s = 0;
  #pragma unroll
  for (int j = 0; j < 8; ++j) {
    int i = base + j;
    int x = (i < len) ? cnt[i] : 0;
    v[j] = s;
    s += x;
  }
  sh[threadIdx.x] = s;
  __syncthreads();
  for (int off = 1; off < 256; off <<= 1) {
    int t = (threadIdx.x >= off) ? sh[threadIdx.x - off] : 0;
    __syncthreads();
    sh[threadIdx.x] += t;
    __syncthreads();
  }
  int texcl = sh[threadIdx.x] - s;
  #pragma unroll
  for (int j = 0; j < 8; ++j) {
    int i = base + j;
    if (i < len) out[i] = texcl + v[j];
  }
  if (threadIdx.x == 255) part[blockIdx.x] = sh[255];
}

__global__ void scan2(int* __restrict__ part, int nb, int* __restrict__ total_out) {
  __shared__ int sh[64];
  int t = threadIdx.x;
  int v = (t < nb) ? part[t] : 0;
  sh[t] = v;
  __syncthreads();
  for (int off = 1; off < 64; off <<= 1) {
    int x = (t >= off) ? sh[t - off] : 0;
    __syncthreads();
    sh[t] += x;
    __syncthreads();
  }
  if (t < nb) part[t] = sh[t] - v;
  if (t == 63) *total_out = sh[63];
}

__global__ __launch_bounds__(256) void scan3(int* __restrict__ offs,
                                             const int* __restrict__ part, int len) {
  int i = blockIdx.x * 256 + threadIdx.x;
  if (i >= len) return;
  offs[i] += part[i >> 11];
}

__global__ __launch_bounds__(512) void fine2(const int* __restrict__ offs,
                                             const int* __restrict__ bcur,
                                             const unsigned long long* __restrict__ rec2,
                                             const int* __restrict__ ovcnt,
                                             const unsigned long long* __restrict__ ovbuf,
                                             unsigned int* __restrict__ pay) {
  int b = blockIdx.x;
  __shared__ int cur[512];
  int t = threadIdx.x;
  {
    int gd = (b << BSH) + t;
    cur[t] = (gd < 70000) ? offs[gd] : 0;
  }
  __syncthreads();
  int nrec = bcur[b];
  nrec = nrec < CAP2 ? nrec : CAP2;
  const unsigned long long* rp = rec2 + (size_t)b * CAP2;
  for (int i = t; i < nrec; i += 512) {
    unsigned long long r = rp[i];
    int ld = (int)(r >> 32) & 511;
    int pos = atomicAdd(&cur[ld], 1);
    if (pos >= 0 && pos < NPAY) pay[pos] = (unsigned)r;  // defensive
  }
  int ovn = *ovcnt;
  ovn = ovn < NOV ? ovn : NOV;
  for (int i = t; i < ovn; i += 512) {
    unsigned long long r = ovbuf[i];
    int gd = (int)(r >> 32);
    if ((gd >> BSH) == b) {
      int pos = atomicAdd(&cur[gd & 511], 1);
      if (pos >= 0 && pos < NPAY) pay[pos] = (unsigned)r;
    }
  }
}

// all 6 relations; one wave per (dst, rel); 4 edges in flight (2 per half-wave)
struct Gather6 { const unsigned short* proj[6]; unsigned short* out[6]; int cb[6]; int n[6]; };
__global__ __launch_bounds__(256) void gather_all(Gather6 g, const int* __restrict__ offs,
                                                  const unsigned int* __restrict__ pay) {
  int rho = blockIdx.y;
  int n = g.n[rho];
  int d = blockIdx.x * 4 + (threadIdx.x >> 6);
  if (d >= n) return;
  int lane = threadIdx.x & 63, half = lane >> 5, l32 = lane & 31;
  const unsigned short* __restrict__ proj = g.proj[rho];
  const int* of = offs + g.cb[rho];
  int s0 = of[d], s1 = of[d + 1];
  float acc[8] = {};
  int e = s0 + half;
  for (; e + 2 < s1; e += 4) {
    unsigned int u0 = pay[e], u1 = pay[e + 2];
    float wt0 = bf2f((unsigned short)(u0 >> 16));
    float wt1 = bf2f((unsigned short)(u1 >> 16));
    s16x8 v0 = *(const s16x8*)(proj + (size_t)(u0 & 0xffffu) * 256 + l32 * 8);
    s16x8 v1 = *(const s16x8*)(proj + (size_t)(u1 & 0xffffu) * 256 + l32 * 8);
    #pragma unroll
    for (int j = 0; j < 8; ++j) {
      acc[j] = fmaf(bf2f((unsigned short)v0[j]), wt0, acc[j]);
      acc[j] = fmaf(bf2f((unsigned short)v1[j]), wt1, acc[j]);
    }
  }
  if (e < s1) {
    unsigned int u = pay[e];
    float wt = bf2f((unsigned short)(u >> 16));
    s16x8 v = *(const s16x8*)(proj + (size_t)(u & 0xffffu) * 256 + l32 * 8);
    #pragma unroll
    for (int j = 0; j < 8; ++j) acc[j] = fmaf(bf2f((unsigned short)v[j]), wt, acc[j]);
  }
  #pragma unroll
  for (int j = 0; j < 8; ++j) acc[j] += __shfl(acc[j], lane ^ 32, 64);
  if (half == 0) {
    s16x8 o;
    #pragma unroll
    for (int j = 0; j < 8; ++j) o[j] = (short)f2bf(acc[j]);
    *(s16x8*)(g.out[rho] + (size_t)d * 256 + l32 * 8) = o;
  }
}

// all 3 types: scores + FAITHFUL reshape(n,2) softmax over adjacent e-pairs
struct Att3 { const unsigned short* nb[3]; const unsigned short* self[3];
              const float* watt[3]; float* att[3]; int n[3]; };
__global__ __launch_bounds__(256) void e_att3(Att3 g) {
  int z = blockIdx.z;
  int n = g.n[z];
  int wv = threadIdx.x >> 6;
  int idx = blockIdx.x * 4 + wv;
  int lane = threadIdx.x & 63;
  __shared__ float ev[4];
  float sum = 0.f;
  if (idx < 2 * n) {
    int i = idx < n ? idx : idx - n;
    ushort4 v  = *(const ushort4*)(g.nb[z] + (size_t)idx * 256 + (lane << 2));
    ushort4 sv = *(const ushort4*)(g.self[z] + (size_t)i * 256 + (lane << 2));
    float4 wa = *(const float4*)(g.watt[z] + (lane << 2));
    float4 wb = *(const float4*)(g.watt[z] + 256 + (lane << 2));
    sum = bf2f(v.x) * wa.x + bf2f(v.y) * wa.y + bf2f(v.z) * wa.z + bf2f(v.w) * wa.w +
          bf2f(sv.x) * wb.x + bf2f(sv.y) * wb.y + bf2f(sv.z) * wb.z + bf2f(sv.w) * wb.w;
    #pragma unroll
    for (int off = 32; off > 0; off >>= 1) sum += __shfl_down(sum, off, 64);
  }
  if (lane == 0) ev[wv] = sum;
  __syncthreads();
  if (threadIdx.x < 2) {
    int base = blockIdx.x * 4 + threadIdx.x * 2;
    if (base < 2 * n) {
      float f0 = ev[threadIdx.x * 2], f1 = ev[threadIdx.x * 2 + 1];
      f0 = f0 > 0.f ? f0 : 0.01f * f0;
      f1 = f1 > 0.f ? f1 : 0.01f * f1;
      float m = fmaxf(f0, f1);
      float a = expf(f0 - m), b = expf(f1 - m);
      float inv = 1.f / (a + b);
      g.att[z][base] = a * inv;
      g.att[z][base + 1] = b * inv;
    }
  }
}

// all 3 types, BM=64/BN=256, 64x64 wave tiles, pipelined staging.
struct Fin3 { const unsigned short* nb[3]; const unsigned short* self[3]; const float* att[3];
              const unsigned short* Wt[3]; const float* bias[3]; float* out[3]; int M[3]; };
__global__ __launch_bounds__(256, 3) void final_mfma3(Fin3 g) {
  int z = blockIdx.z;
  int M = g.M[z];
  int row0 = blockIdx.y * 64;
  if (row0 >= M) return;
  const unsigned short* __restrict__ nbft = g.nb[z];
  const unsigned short* __restrict__ selfb = g.self[z];
  const float* __restrict__ att = g.att[z];
  const unsigned short* __restrict__ Wt = g.Wt[z];
  __shared__ unsigned short As[64 * 40];
  __shared__ unsigned short Bs[256 * 40];
  int tid = threadIdx.x, lane = tid & 63, w = tid >> 6;
  int quad = lane >> 4, m16 = lane & 15;
  int am = tid >> 2, akk = (tid & 3) * 8;
  int gr = row0 + am;
  float a0 = 0.f, a1 = 0.f;
  if (gr < M) { a0 = att[2 * gr]; a1 = att[2 * gr + 1]; }
  f32x4 acc[4][4];
  #pragma unroll
  for (int r = 0; r < 4; ++r)
    #pragma unroll
    for (int c = 0; c < 4; ++c) acc[r][c] = (f32x4){0.f, 0.f, 0.f, 0.f};

  s16x8 pu0 = {}, pu1 = {};
  s16x8 pb[4];

  auto loadA = [&](int k0) {
    int kg = k0 + akk;
    if (gr < M) {
      if (kg < 256) {
        pu0 = *(const s16x8*)(nbft + (size_t)gr * 256 + kg);
        pu1 = *(const s16x8*)(nbft + ((size_t)M + gr) * 256 + kg);
      } else {
        pu0 = *(const s16x8*)(selfb + (size_t)gr * 256 + (kg - 256));
      }
    }
  };
  auto loadB = [&](int k0) {
    #pragma unroll
    for (int i = 0; i < 4; ++i) {
      int ch = tid + i * 256;
      int m = ch >> 2, kk = (ch & 3) * 8;
      pb[i] = *(const s16x8*)(Wt + (size_t)m * 512 + k0 + kk);
    }
  };
  auto storeLDS = [&](int k0) {
    int kg = k0 + akk;
    s16x8 v = {};
    if (gr < M) {
      if (kg < 256) {
        #pragma unroll
        for (int j = 0; j < 8; ++j)
          v[j] = (short)f2bf(fmaf(a0, bf2f((unsigned short)pu0[j]),
                                  a1 * bf2f((unsigned short)pu1[j])));
      } else {
        v = pu0;
      }
    }
    *(s16x8*)&As[am * 40 + akk] = v;
    #pragma unroll
    for (int i = 0; i < 4; ++i) {
      int ch = tid + i * 256;
      int m = ch >> 2, kk = (ch & 3) * 8;
      *(s16x8*)&Bs[m * 40 + kk] = pb[i];
    }
  };

  loadA(0); loadB(0); storeLDS(0);
  __syncthreads();
  for (int k0 = 0; k0 < 512; k0 += 32) {
    int kn = k0 + 32;
    if (kn < 512) { loadA(kn); loadB(kn); }
    s16x8 af[4], bf[4];
    #pragma unroll
    for (int r = 0; r < 4; ++r)
      af[r] = *(const s16x8*)&As[(r * 16 + m16) * 40 + quad * 8];
    #pragma unroll
    for (int c = 0; c < 4; ++c)
      bf[c] = *(const s16x8*)&Bs[(w * 64 + c * 16 + m16) * 40 + quad * 8];
    #pragma unroll
    for (int r = 0; r < 4; ++r)
      #pragma unroll
      for (int c = 0; c < 4; ++c)
        acc[r][c] = __builtin_amdgcn_mfma_f32_16x16x32_bf16(af[r], bf[c], acc[r][c], 0, 0, 0);
    __syncthreads();
    if (kn < 512) {
      storeLDS(kn);
      __syncthreads();
    }
  }
  const float* __restrict__ bias = g.bias[z];
  float* __restrict__ out = g.out[z];
  #pragma unroll
  for (int r = 0; r < 4; ++r)
    #pragma unroll
    for (int i = 0; i < 4; ++i) {
      int row = row0 + r * 16 + quad * 4 + i;
      if (row < M) {
        #pragma unroll
        for (int c = 0; c < 4; ++c) {
          int col = w * 64 + c * 16 + m16;
          out[(size_t)row * 256 + col] = acc[r][c][i] + bias[col];
        }
      }
    }
}

} // namespace

extern "C" void kernel_launch(void* const* d_in, const int* in_sizes, int n_in,
                              void* d_out, int out_size, void* d_ws, size_t ws_size,
                              hipStream_t stream) {
  (void)in_sizes; (void)n_in; (void)out_size; (void)ws_size;
  const float* x[3] = {(const float*)d_in[0], (const float*)d_in[1], (const float*)d_in[2]};

  // ---- workspace layout ----
  char* p = (char*)d_ws;
  unsigned short* projfull = (unsigned short*)p;  p += (size_t)105000 * 256 * 2;
  unsigned short* nbft = (unsigned short*)p;      p += (size_t)70000 * 256 * 2;
  unsigned short* wcatbt = (unsigned short*)p;    p += (size_t)3 * 256 * 512 * 2;
  int* offs = (int*)p;                            p += (size_t)70004 * 4;
  int* counts = (int*)p;                          p += (size_t)70000 * 4;   // zeroed
  int* bcur = (int*)p;                            p += 160 * 4;             // zeroed
  int* ovcnt = (int*)p;                           p += 16;                  // zeroed
  int* part = (int*)p;                            p += 256;
  float* att_buf = (float*)p;                     p += (size_t)70000 * 4;
  unsigned int* csr_pay = (unsigned int*)p;       p += (size_t)1120000 * 4;
  // aliases into nbft (dead until gather_all):
  unsigned short* wshT = nbft;
  unsigned short* Wcbt = (unsigned short*)((char*)nbft + 393216);
  // record buffers alias projfull (dead until proj_mfma9 overwrites all rows):
  unsigned long long* rec2 = (unsigned long long*)projfull;            // 11.2 MB
  unsigned long long* ovbuf = rec2 + (size_t)NB2 * CAP2;               // 0.5 MB
  // bf16 copy of x lives in d_out (dead until final_mfma3 writes real output):
  unsigned short* xb = (unsigned short*)d_out;

  const int n_of[3] = {20000, 10000, 5000};
  const int nbt[3][2] = {{1, 2}, {0, 2}, {0, 1}};
  const int ebase[3][2] = {{3, 6}, {9, 12}, {15, 18}};
  const int nE3[3] = {320000, 160000, 80000};
  const size_t out_off[3] = {0, (size_t)20000 * 256, (size_t)30000 * 256};
  const int tstart[3] = {0, 15000, 40000};
  const int selfoff[3] = {70000, 90000, 100000};
  const int nboff[3] = {0, 40000, 60000};
  const int xboff[3] = {0, 20000, 30000};

  // ---- x -> bf16 ----
  cvt_x3<<<dim3(8750), 256, 0, stream>>>(x[0], x[1], x[2], xb);

  // ---- transpose+cvt: 3 wsh, 3 wcat ----
  Tc6 tc;
  for (int t = 0; t < 3; ++t) {
    tc.src[t] = (const float*)d_in[21 + t * 7 + 3];
    tc.dst[t] = wshT + (size_t)t * 256 * 256;
    tc.R[t] = 256;
    tc.src[3 + t] = (const float*)d_in[21 + t * 7 + 5];
    tc.dst[3 + t] = wcatbt + (size_t)t * 256 * 512;
    tc.R[3 + t] = 512;
  }
  transpose_cvt<<<dim3(8, 16, 6), 256, 0, stream>>>(tc);

  // ---- combined weights via MFMA ----
  Comb9 c9;
  for (int t = 0; t < 3; ++t) {
    int wb = 21 + t * 7;
    for (int j = 0; j < 3; ++j) {
      int combo = t * 3 + j;
      c9.A[combo] = wshT + (size_t)t * 256 * 256;
      c9.B[combo] = (const float*)d_in[wb + j];
      c9.C[combo] = Wcbt + (size_t)combo * 256 * 512;
    }
  }
  combine_mfma<<<dim3(4, 2, 9), 256, 0, stream>>>(c9);

  // ---- CSR build (LDS-staged two-level counting sort) ----
  Edges6 ep;
  const int cbase[6] = {0, 20000, 40000, 50000, 60000, 65000};
  for (int t = 0; t < 3; ++t)
    for (int r = 0; r < 2; ++r) {
      int rho = t * 2 + r, eb = ebase[t][r];
      ep.src[rho] = (const int*)d_in[eb];
      ep.dst[rho] = (const int*)d_in[eb + 1];
      ep.w[rho] = (const float*)d_in[eb + 2];
      ep.nE[rho] = nE3[t];
      ep.cbase[rho] = cbase[rho];
    }
  // zero counts + bcur + ovcnt in one memset (contiguous by layout)
  hipMemsetAsync(counts, 0, (size_t)70000 * 4 + 160 * 4 + 16, stream);
  bin1<<<dim3(313, 6), 256, 0, stream>>>(ep, counts, bcur, ovcnt, rec2, ovbuf);
  scan1<<<35, 256, 0, stream>>>(counts, offs, part, 70000);
  scan2<<<1, 64, 0, stream>>>(part, 35, offs + 70000);
  scan3<<<274, 256, 0, stream>>>(offs, part, 70000);
  fine2<<<NB2, 512, 0, stream>>>(offs, bcur, rec2, ovcnt, ovbuf, csr_pay);

  // ---- all 9 projections, one launch (128x128 tiles, global_load_lds) ----
  Proj9 pj;
  for (int t = 0; t < 3; ++t) {
    int nb0 = nbt[t][0], nb1 = nbt[t][1];
    int m0 = n_of[nb0];
    pj.A[t * 3 + 0] = xb + (size_t)xboff[nb0] * 512;
    pj.C[t * 3 + 0] = projfull + (size_t)tstart[t] * 256;
    pj.M[t * 3 + 0] = m0;
    pj.A[t * 3 + 1] = xb + (size_t)xboff[nb1] * 512;
    pj.C[t * 3 + 1] = projfull + (size_t)(tstart[t] + m0) * 256;
    pj.M[t * 3 + 1] = n_of[nb1];
    pj.A[t * 3 + 2] = xb + (size_t)xboff[t] * 512;
    pj.C[t * 3 + 2] = projfull + (size_t)selfoff[t] * 256;
    pj.M[t * 3 + 2] = n_of[t];
    for (int j = 0; j < 3; ++j)
      pj.Bt[t * 3 + j] = Wcbt + (size_t)(t * 3 + j) * 256 * 512;
  }
  proj_mfma9<<<dim3(2, 157, 9), 256, 0, stream>>>(pj);

  // ---- all 6 gathers, one launch ----
  Gather6 gt;
  for (int t = 0; t < 3; ++t) {
    int m0 = n_of[nbt[t][0]];
    for (int r = 0; r < 2; ++r) {
      int rho = t * 2 + r;
      gt.proj[rho] = projfull + (size_t)(tstart[t] + (r ? m0 : 0)) * 256;
      gt.out[rho] = nbft + (size_t)(nboff[t] + r * n_of[t]) * 256;
      gt.cb[rho] = cbase[rho];
      gt.n[rho] = n_of[t];
    }
  }
  gather_all<<<dim3(5000, 6), 256, 0, stream>>>(gt, offs, csr_pay);

  // ---- attention (3 types) ----
  Att3 at;
  for (int t = 0; t < 3; ++t) {
    at.nb[t] = nbft + (size_t)nboff[t] * 256;
    at.self[t] = projfull + (size_t)selfoff[t] * 256;
    at.watt[t] = (const float*)d_in[21 + t * 7 + 4];
    at.att[t] = att_buf + nboff[t];
    at.n[t] = n_of[t];
  }
  e_att3<<<dim3(10000, 1, 3), 256, 0, stream>>>(at);

  // ---- final GEMM (3 types, BM=64, 64x64 wave tiles) ----
  Fin3 fn;
  for (int t = 0; t < 3; ++t) {
    fn.nb[t] = nbft + (size_t)nboff[t] * 256;
    fn.self[t] = projfull + (size_t)selfoff[t] * 256;
    fn.att[t] = att_buf + nboff[t];
    fn.Wt[t] = wcatbt + (size_t)t * 256 * 512;
    fn.bias[t] = (const float*)d_in[21 + t * 7 + 6];
    fn.out[t] = (float*)d_out + out_off[t];
    fn.M[t] = n_of[t];
  }
  final_mfma3<<<dim3(1, 313, 3), 256, 0, stream>>>(fn);
}

// Round 7
// 406.407 us; speedup vs baseline: 1.3466x; 1.0662x over previous
//
#include <hip/hip_runtime.h>

namespace {

typedef short s16x8 __attribute__((ext_vector_type(8)));
typedef float f32x4 __attribute__((ext_vector_type(4)));

__device__ __forceinline__ float bf2f(unsigned short u) {
  return __uint_as_float(((unsigned)u) << 16);
}
__device__ __forceinline__ unsigned short f2bf(float f) {
  unsigned u = __float_as_uint(f);
  u += 0x7fffu + ((u >> 16) & 1u);
  return (unsigned short)(u >> 16);
}

// async global->LDS, 16B per lane. LDS dest is wave-uniform base + lane*16.
typedef __attribute__((address_space(3))) unsigned int lds_u32;
typedef __attribute__((address_space(1))) const unsigned int glob_u32;
__device__ __forceinline__ void gl16(const void* g, void* l) {
  __builtin_amdgcn_global_load_lds((glob_u32*)g, (lds_u32*)l, 16, 0, 0);
}

// x (fp32) -> xb (bf16), 35000x512 total; xb lives in d_out (dead until final_mfma3).
__global__ __launch_bounds__(256) void cvt_x3(const float* __restrict__ x0,
                                              const float* __restrict__ x1,
                                              const float* __restrict__ x2,
                                              unsigned short* __restrict__ out) {
  size_t i = ((size_t)blockIdx.x * 256 + threadIdx.x) * 8;
  const float* src;
  size_t off;
  if (i < (size_t)20000 * 512) { src = x0; off = i; }
  else if (i < (size_t)30000 * 512) { src = x1; off = i - (size_t)20000 * 512; }
  else { src = x2; off = i - (size_t)30000 * 512; }
  float4 a = *(const float4*)(src + off);
  float4 b = *(const float4*)(src + off + 4);
  s16x8 v;
  v[0] = (short)f2bf(a.x); v[1] = (short)f2bf(a.y);
  v[2] = (short)f2bf(a.z); v[3] = (short)f2bf(a.w);
  v[4] = (short)f2bf(b.x); v[5] = (short)f2bf(b.y);
  v[6] = (short)f2bf(b.z); v[7] = (short)f2bf(b.w);
  *(s16x8*)(out + i) = v;
}

// fp32 [R][256] -> bf16 [256][R] (transposed). wsh: R=256, wcat: R=512.
struct Tc6 { const float* src[6]; unsigned short* dst[6]; int R[6]; };
__global__ __launch_bounds__(256) void transpose_cvt(Tc6 a) {
  int mat = blockIdx.z;
  int R = a.R[mat];
  int r0 = blockIdx.y * 32, c0 = blockIdx.x * 32;
  if (r0 >= R) return;
  const float* __restrict__ src = a.src[mat];
  unsigned short* __restrict__ dst = a.dst[mat];
  __shared__ float T[32][33];
  int tx = threadIdx.x & 31, ty = threadIdx.x >> 5;
  #pragma unroll
  for (int j = 0; j < 4; ++j) {
    int r = ty + j * 8;
    T[r][tx] = src[(size_t)(r0 + r) * 256 + c0 + tx];
  }
  __syncthreads();
  #pragma unroll
  for (int j = 0; j < 4; ++j) {
    int c = ty + j * 8;
    dst[(size_t)(c0 + c) * R + r0 + tx] = f2bf(T[tx][c]);
  }
}

// Wcbt[256x512] = wshT[256x256](bf16) @ W[512x256]^T(fp32, cvt on load)
struct Comb9 { const unsigned short* A[9]; const float* B[9]; unsigned short* C[9]; };
__global__ __launch_bounds__(256) void combine_mfma(Comb9 g) {
  int z = blockIdx.z;
  const unsigned short* __restrict__ A = g.A[z];
  const float* __restrict__ B = g.B[z];
  unsigned short* __restrict__ C = g.C[z];
  int row0 = blockIdx.y * 128;
  int col0 = blockIdx.x * 128;
  __shared__ unsigned short As[128 * 40];
  __shared__ unsigned short Bs[128 * 40];
  int tid = threadIdx.x, lane = tid & 63, w = tid >> 6;
  int quad = lane >> 4, m16 = lane & 15;
  f32x4 acc[2][8];
  #pragma unroll
  for (int r = 0; r < 2; ++r)
    #pragma unroll
    for (int c = 0; c < 8; ++c) acc[r][c] = (f32x4){0.f, 0.f, 0.f, 0.f};
  for (int k0 = 0; k0 < 256; k0 += 32) {
    #pragma unroll
    for (int i = 0; i < 2; ++i) {
      int ch = tid + i * 256;
      int m = ch >> 2, kk = (ch & 3) * 8;
      *(s16x8*)&As[m * 40 + kk] = *(const s16x8*)(A + (size_t)(row0 + m) * 256 + k0 + kk);
      const float4* bp = (const float4*)(B + (size_t)(col0 + m) * 256 + k0 + kk);
      float4 b0 = bp[0], b1 = bp[1];
      s16x8 bv;
      bv[0] = (short)f2bf(b0.x); bv[1] = (short)f2bf(b0.y);
      bv[2] = (short)f2bf(b0.z); bv[3] = (short)f2bf(b0.w);
      bv[4] = (short)f2bf(b1.x); bv[5] = (short)f2bf(b1.y);
      bv[6] = (short)f2bf(b1.z); bv[7] = (short)f2bf(b1.w);
      *(s16x8*)&Bs[m * 40 + kk] = bv;
    }
    __syncthreads();
    s16x8 af[2], bf[8];
    #pragma unroll
    for (int r = 0; r < 2; ++r)
      af[r] = *(const s16x8*)&As[(w * 32 + r * 16 + m16) * 40 + quad * 8];
    #pragma unroll
    for (int c = 0; c < 8; ++c)
      bf[c] = *(const s16x8*)&Bs[(c * 16 + m16) * 40 + quad * 8];
    #pragma unroll
    for (int r = 0; r < 2; ++r)
      #pragma unroll
      for (int c = 0; c < 8; ++c)
        acc[r][c] = __builtin_amdgcn_mfma_f32_16x16x32_bf16(af[r], bf[c], acc[r][c], 0, 0, 0);
    __syncthreads();
  }
  #pragma unroll
  for (int r = 0; r < 2; ++r)
    #pragma unroll
    for (int i = 0; i < 4; ++i) {
      int row = row0 + w * 32 + r * 16 + quad * 4 + i;
      #pragma unroll
      for (int c = 0; c < 8; ++c)
        C[(size_t)row * 512 + col0 + c * 16 + m16] = f2bf(acc[r][c][i]);
    }
}

// 9 projections, one launch. m97 structure: 128x128 tile, BK=32, 4 waves x 64x64,
// single-buffered linear LDS, global_load_lds width-16 for both A (bf16) and B (bf16).
struct Proj9 { const unsigned short* A[9]; const unsigned short* Bt[9]; unsigned short* C[9]; int M[9]; };
__global__ __launch_bounds__(256) void proj_mfma9(Proj9 g) {
  int z = blockIdx.z;
  int M = g.M[z];
  int row0 = blockIdx.y * 128;
  if (row0 >= M) return;
  int col0 = blockIdx.x * 128;
  const unsigned short* __restrict__ A = g.A[z];
  const unsigned short* __restrict__ Bt = g.Bt[z];
  unsigned short* __restrict__ C = g.C[z];
  __shared__ unsigned short As[128 * 32];
  __shared__ unsigned short Bs[128 * 32];
  int tid = threadIdx.x, lane = tid & 63, w = tid >> 6;
  int quad = lane >> 4, m16 = lane & 15;
  int lr = lane >> 2, lk = (lane & 3) * 8;
  int r0g = row0 + w * 32 + lr;
  int r1g = r0g + 16;
  const unsigned short* a0p = A + (size_t)(r0g < M ? r0g : M - 1) * 512 + lk;
  const unsigned short* a1p = A + (size_t)(r1g < M ? r1g : M - 1) * 512 + lk;
  const unsigned short* b0p = Bt + (size_t)(col0 + w * 32 + lr) * 512 + lk;
  const unsigned short* b1p = b0p + (size_t)16 * 512;
  unsigned short* as0 = &As[w * 1024];
  unsigned short* as1 = &As[w * 1024 + 512];
  unsigned short* bs0 = &Bs[w * 1024];
  unsigned short* bs1 = &Bs[w * 1024 + 512];
  int wr = (w & 1) * 64, wc = (w >> 1) * 64;
  f32x4 acc[4][4];
  #pragma unroll
  for (int r = 0; r < 4; ++r)
    #pragma unroll
    for (int c = 0; c < 4; ++c) acc[r][c] = (f32x4){0.f, 0.f, 0.f, 0.f};
  for (int k0 = 0; k0 < 512; k0 += 32) {
    gl16(a0p + k0, as0);
    gl16(a1p + k0, as1);
    gl16(b0p + k0, bs0);
    gl16(b1p + k0, bs1);
    __syncthreads();
    s16x8 af[4], bf[4];
    #pragma unroll
    for (int r = 0; r < 4; ++r)
      af[r] = *(const s16x8*)&As[(wr + r * 16 + m16) * 32 + quad * 8];
    #pragma unroll
    for (int c = 0; c < 4; ++c)
      bf[c] = *(const s16x8*)&Bs[(wc + c * 16 + m16) * 32 + quad * 8];
    #pragma unroll
    for (int r = 0; r < 4; ++r)
      #pragma unroll
      for (int c = 0; c < 4; ++c)
        acc[r][c] = __builtin_amdgcn_mfma_f32_16x16x32_bf16(af[r], bf[c], acc[r][c], 0, 0, 0);
    __syncthreads();
  }
  #pragma unroll
  for (int r = 0; r < 4; ++r)
    #pragma unroll
    for (int i = 0; i < 4; ++i) {
      int row = row0 + wr + r * 16 + quad * 4 + i;
      if (row < M) {
        #pragma unroll
        for (int c = 0; c < 4; ++c)
          C[(size_t)row * 256 + col0 + wc + c * 16 + m16] = f2bf(acc[r][c][i]);
      }
    }
}

struct Edges6 { const int* src[6]; const int* dst[6]; const float* w[6]; int nE[6]; int cbase[6]; };

// ---- CSR build: LDS-staged two-level counting sort ----
// bin1: per 1024-edge chunk, LDS histogram into 137 coarse buckets, wave-shuffle
// scan, stage bucket-sorted in LDS, reserve a 64B-ALIGNED range per bucket
// (rv=(hv+7)&~7, sentinel-padded) -> every rec2 line written by exactly one
// block: no scattered-atomic ping-pong (round-6 PMC: the per-dst counts
// histogram was ~30MB of cross-XCD line writebacks; now derived in cnt2).
// cnt2: per bucket, LDS histogram of 512 dsts from rec2 records, dense write.
// fine2: per bucket, LDS cursors from offs, final 4B payloads into the
// bucket's contiguous csr_pay window. Sentinels (gd<0) skipped everywhere.
#define BSH 9
#define NB2 137            // ceil(70000 / 512)
#define CAP2 16384         // padded mean ~12.3K; std ~90 -> huge margin + overflow path
#define NOV 65536
#define CH 1024
#define NPAY 1120000

__global__ __launch_bounds__(256) void bin1(Edges6 ep,
                                            int* __restrict__ bcur, int* __restrict__ ovcnt,
                                            unsigned long long* __restrict__ rec2,
                                            unsigned long long* __restrict__ ovbuf) {
  int rho = blockIdx.y;
  int nE = ep.nE[rho];
  int chunk = blockIdx.x * CH;
  if (chunk >= nE) return;
  int n = nE - chunk; if (n > CH) n = CH;
  const int* __restrict__ srcp = ep.src[rho];
  const int* __restrict__ dstp = ep.dst[rho];
  const float* __restrict__ wp = ep.w[rho];
  int cb = ep.cbase[rho];
  __shared__ int h[256], excl[256], lcur[256], gbase[256], rsv[256];
  __shared__ int wsum[4];
  __shared__ unsigned long long stage[CH];
  int t = threadIdx.x;
  h[t] = 0;
  gbase[t] = 0;
  __syncthreads();
  int gd[4]; unsigned pv[4];
  #pragma unroll
  for (int j = 0; j < 4; ++j) {
    int idx = t + j * 256;
    gd[j] = -1;
    if (idx < n) {
      int e = chunk + idx;
      int g = cb + dstp[e];
      if (g < 0) g = 0;
      if (g > 69999) g = 69999;       // defensive (inputs guarantee in-range)
      gd[j] = g;
      pv[j] = (((unsigned)f2bf(wp[e])) << 16) | ((unsigned)srcp[e] & 0x7fffu);
      atomicAdd(&h[g >> BSH], 1);
    }
  }
  __syncthreads();
  int hv = h[t];
  // wave-shuffle inclusive scan over 256 entries (4 waves x 64 lanes)
  int lane = t & 63, wv = t >> 6;
  int v = hv;
  #pragma unroll
  for (int off = 1; off < 64; off <<= 1) {
    int u = __shfl_up(v, off, 64);
    if (lane >= off) v += u;
  }
  if (lane == 63) wsum[wv] = v;
  __syncthreads();
  int add = 0;
  #pragma unroll
  for (int k = 0; k < 3; ++k)
    if (k < wv) add += wsum[k];
  v += add;
  int ex = v - hv;
  excl[t] = ex;
  lcur[t] = ex;
  int rv = 0;
  if (t < NB2 && hv > 0) {
    rv = (hv + 7) & ~7;               // 64B-aligned reservation
    gbase[t] = atomicAdd(&bcur[t], rv);
  }
  rsv[t] = rv;
  __syncthreads();
  // stage records bucket-sorted in LDS
  #pragma unroll
  for (int j = 0; j < 4; ++j) {
    if (gd[j] >= 0) {
      int b = gd[j] >> BSH;
      int slot = atomicAdd(&lcur[b], 1);
      if (slot >= 0 && slot < CH)     // defensive (sum of h == n <= CH)
        stage[slot] = ((unsigned long long)(unsigned)gd[j] << 32) | pv[j];
    }
  }
  __syncthreads();
  // coalesced burst write-out (records)
  for (int s = t; s < n; s += 256) {
    int lo = 0, hi = NB2 - 1;
    while (lo < hi) {
      int mid = (lo + hi + 1) >> 1;
      if (excl[mid] <= s) lo = mid; else hi = mid - 1;
    }
    int b = lo;
    int gp = gbase[b] + (s - excl[b]);
    if (gp >= 0 && gp < CAP2) rec2[(size_t)b * CAP2 + gp] = stage[s];
    else { int op = atomicAdd(ovcnt, 1); ovbuf[op & (NOV - 1)] = stage[s]; }
  }
  // sentinel fill of reserved tails (same lines as our own records only)
  for (int b = t; b < NB2; b += 256) {
    int hvb = h[b], rvb = rsv[b], gb = gbase[b];
    for (int k = hvb; k < rvb; ++k) {
      int gp = gb + k;
      if (gp >= 0 && gp < CAP2) rec2[(size_t)b * CAP2 + gp] = 0xFFFFFFFFFFFFFFFFull;
    }
  }
}

// per-dst counts derived from the bucket-sorted records (dense read + dense write)
__global__ __launch_bounds__(256) void cnt2(const int* __restrict__ bcur,
                                            const unsigned long long* __restrict__ rec2,
                                            const int* __restrict__ ovcnt,
                                            const unsigned long long* __restrict__ ovbuf,
                                            int* __restrict__ counts) {
  int b = blockIdx.x;
  __shared__ int c[512];
  int t = threadIdx.x;
  c[t] = 0; c[t + 256] = 0;
  __syncthreads();
  int nrec = bcur[b];
  nrec = nrec < CAP2 ? nrec : CAP2;
  const unsigned long long* rp = rec2 + (size_t)b * CAP2;
  for (int i = t; i < nrec; i += 256) {
    int gd = (int)(rp[i] >> 32);
    if (gd >= 0) atomicAdd(&c[gd & 511], 1);
  }
  int ovn = *ovcnt;
  ovn = ovn < NOV ? ovn : NOV;
  for (int i = t; i < ovn; i += 256) {
    int gd = (int)(ovbuf[i] >> 32);
    if (gd >= 0 && (gd >> BSH) == b) atomicAdd(&c[gd & 511], 1);
  }
  __syncthreads();
  int g0 = (b << BSH) + t;
  if (g0 < 70000) counts[g0] = c[t];
  int g1 = g0 + 256;
  if (g1 < 70000) counts[g1] = c[t + 256];
}

__global__ __launch_bounds__(256) void scan1(const int* __restrict__ cnt, int* __restrict__ out,
                                             int* __restrict__ part, int len) {
  __shared__ int sh[256];
  int base = blockIdx.x * 2048 + threadIdx.x * 8;
  int v[8];
  int s = 0;
  #pragma unroll
  for (int j = 0; j < 8; ++j) {
    int i = base + j;
    int x = (i < len) ? cnt[i] : 0;
    v[j] = s;
    s += x;
  }
  sh[threadIdx.x] = s;
  __syncthreads();
  for (int off = 1; off < 256; off <<= 1) {
    int t = (threadIdx.x >= off) ? sh[threadIdx.x - off] : 0;
    __syncthreads();
    sh[threadIdx.x] += t;
    __syncthreads();
  }
  int texcl = sh[threadIdx.x] - s;
  #pragma unroll
  for (int j = 0; j < 8; ++j) {
    int i = base + j;
    if (i < len) out[i] = texcl + v[j];
  }
  if (threadIdx.x == 255) part[blockIdx.x] = sh[255];
}

__global__ void scan2(int* __restrict__ part, int nb, int* __restrict__ total_out) {
  __shared__ int sh[64];
  int t = threadIdx.x;
  int v = (t < nb) ? part[t] : 0;
  sh[t] = v;
  __syncthreads();
  for (int off = 1; off < 64; off <<= 1) {
    int x = (t >= off) ? sh[t - off] : 0;
    __syncthreads();
    sh[t] += x;
    __syncthreads();
  }
  if (t < nb) part[t] = sh[t] - v;
  if (t == 63) *total_out = sh[63];
}

__global__ __launch_bounds__(256) void scan3(int* __restrict__ offs,
                                             const int* __restrict__ part, int len) {
  int i = blockIdx.x * 256 + threadIdx.x;
  if (i >= len) return;
  offs[i] += part[i >> 11];
}

__global__ __launch_bounds__(512) void fine2(const int* __restrict__ offs,
                                             const int* __restrict__ bcur,
                                             const unsigned long long* __restrict__ rec2,
                                             const int* __restrict__ ovcnt,
                                             const unsigned long long* __restrict__ ovbuf,
                                             unsigned int* __restrict__ pay) {
  int b = blockIdx.x;
  __shared__ int cur[512];
  int t = threadIdx.x;
  {
    int gd = (b << BSH) + t;
    cur[t] = (gd < 70000) ? offs[gd] : 0;
  }
  __syncthreads();
  int nrec = bcur[b];
  nrec = nrec < CAP2 ? nrec : CAP2;
  const unsigned long long* rp = rec2 + (size_t)b * CAP2;
  for (int i = t; i < nrec; i += 512) {
    unsigned long long r = rp[i];
    int gd = (int)(r >> 32);
    if (gd < 0) continue;             // sentinel pad
    int pos = atomicAdd(&cur[gd & 511], 1);
    if (pos >= 0 && pos < NPAY) pay[pos] = (unsigned)r;  // defensive
  }
  int ovn = *ovcnt;
  ovn = ovn < NOV ? ovn : NOV;
  for (int i = t; i < ovn; i += 512) {
    unsigned long long r = ovbuf[i];
    int gd = (int)(r >> 32);
    if (gd >= 0 && (gd >> BSH) == b) {
      int pos = atomicAdd(&cur[gd & 511], 1);
      if (pos >= 0 && pos < NPAY) pay[pos] = (unsigned)r;
    }
  }
}

// all 6 relations; one wave per (dst, rel); 4 edges in flight (2 per half-wave)
struct Gather6 { const unsigned short* proj[6]; unsigned short* out[6]; int cb[6]; int n[6]; };
__global__ __launch_bounds__(256) void gather_all(Gather6 g, const int* __restrict__ offs,
                                                  const unsigned int* __restrict__ pay) {
  int rho = blockIdx.y;
  int n = g.n[rho];
  int d = blockIdx.x * 4 + (threadIdx.x >> 6);
  if (d >= n) return;
  int lane = threadIdx.x & 63, half = lane >> 5, l32 = lane & 31;
  const unsigned short* __restrict__ proj = g.proj[rho];
  const int* of = offs + g.cb[rho];
  int s0 = of[d], s1 = of[d + 1];
  float acc[8] = {};
  int e = s0 + half;
  for (; e + 2 < s1; e += 4) {
    unsigned int u0 = pay[e], u1 = pay[e + 2];
    float wt0 = bf2f((unsigned short)(u0 >> 16));
    float wt1 = bf2f((unsigned short)(u1 >> 16));
    s16x8 v0 = *(const s16x8*)(proj + (size_t)(u0 & 0xffffu) * 256 + l32 * 8);
    s16x8 v1 = *(const s16x8*)(proj + (size_t)(u1 & 0xffffu) * 256 + l32 * 8);
    #pragma unroll
    for (int j = 0; j < 8; ++j) {
      acc[j] = fmaf(bf2f((unsigned short)v0[j]), wt0, acc[j]);
      acc[j] = fmaf(bf2f((unsigned short)v1[j]), wt1, acc[j]);
    }
  }
  if (e < s1) {
    unsigned int u = pay[e];
    float wt = bf2f((unsigned short)(u >> 16));
    s16x8 v = *(const s16x8*)(proj + (size_t)(u & 0xffffu) * 256 + l32 * 8);
    #pragma unroll
    for (int j = 0; j < 8; ++j) acc[j] = fmaf(bf2f((unsigned short)v[j]), wt, acc[j]);
  }
  #pragma unroll
  for (int j = 0; j < 8; ++j) acc[j] += __shfl(acc[j], lane ^ 32, 64);
  if (half == 0) {
    s16x8 o;
    #pragma unroll
    for (int j = 0; j < 8; ++j) o[j] = (short)f2bf(acc[j]);
    *(s16x8*)(g.out[rho] + (size_t)d * 256 + l32 * 8) = o;
  }
}

// all 3 types: scores + FAITHFUL reshape(n,2) softmax over adjacent e-pairs
struct Att3 { const unsigned short* nb[3]; const unsigned short* self[3];
              const float* watt[3]; float* att[3]; int n[3]; };
__global__ __launch_bounds__(256) void e_att3(Att3 g) {
  int z = blockIdx.z;
  int n = g.n[z];
  int wv = threadIdx.x >> 6;
  int idx = blockIdx.x * 4 + wv;
  int lane = threadIdx.x & 63;
  __shared__ float ev[4];
  float sum = 0.f;
  if (idx < 2 * n) {
    int i = idx < n ? idx : idx - n;
    ushort4 v  = *(const ushort4*)(g.nb[z] + (size_t)idx * 256 + (lane << 2));
    ushort4 sv = *(const ushort4*)(g.self[z] + (size_t)i * 256 + (lane << 2));
    float4 wa = *(const float4*)(g.watt[z] + (lane << 2));
    float4 wb = *(const float4*)(g.watt[z] + 256 + (lane << 2));
    sum = bf2f(v.x) * wa.x + bf2f(v.y) * wa.y + bf2f(v.z) * wa.z + bf2f(v.w) * wa.w +
          bf2f(sv.x) * wb.x + bf2f(sv.y) * wb.y + bf2f(sv.z) * wb.z + bf2f(sv.w) * wb.w;
    #pragma unroll
    for (int off = 32; off > 0; off >>= 1) sum += __shfl_down(sum, off, 64);
  }
  if (lane == 0) ev[wv] = sum;
  __syncthreads();
  if (threadIdx.x < 2) {
    int base = blockIdx.x * 4 + threadIdx.x * 2;
    if (base < 2 * n) {
      float f0 = ev[threadIdx.x * 2], f1 = ev[threadIdx.x * 2 + 1];
      f0 = f0 > 0.f ? f0 : 0.01f * f0;
      f1 = f1 > 0.f ? f1 : 0.01f * f1;
      float m = fmaxf(f0, f1);
      float a = expf(f0 - m), b = expf(f1 - m);
      float inv = 1.f / (a + b);
      g.att[z][base] = a * inv;
      g.att[z][base + 1] = b * inv;
    }
  }
}

// all 3 types, BM=64/BN=256, 64x64 wave tiles, pipelined staging.
struct Fin3 { const unsigned short* nb[3]; const unsigned short* self[3]; const float* att[3];
              const unsigned short* Wt[3]; const float* bias[3]; float* out[3]; int M[3]; };
__global__ __launch_bounds__(256, 3) void final_mfma3(Fin3 g) {
  int z = blockIdx.z;
  int M = g.M[z];
  int row0 = blockIdx.y * 64;
  if (row0 >= M) return;
  const unsigned short* __restrict__ nbft = g.nb[z];
  const unsigned short* __restrict__ selfb = g.self[z];
  const float* __restrict__ att = g.att[z];
  const unsigned short* __restrict__ Wt = g.Wt[z];
  __shared__ unsigned short As[64 * 40];
  __shared__ unsigned short Bs[256 * 40];
  int tid = threadIdx.x, lane = tid & 63, w = tid >> 6;
  int quad = lane >> 4, m16 = lane & 15;
  int am = tid >> 2, akk = (tid & 3) * 8;
  int gr = row0 + am;
  float a0 = 0.f, a1 = 0.f;
  if (gr < M) { a0 = att[2 * gr]; a1 = att[2 * gr + 1]; }
  f32x4 acc[4][4];
  #pragma unroll
  for (int r = 0; r < 4; ++r)
    #pragma unroll
    for (int c = 0; c < 4; ++c) acc[r][c] = (f32x4){0.f, 0.f, 0.f, 0.f};

  s16x8 pu0 = {}, pu1 = {};
  s16x8 pb[4];

  auto loadA = [&](int k0) {
    int kg = k0 + akk;
    if (gr < M) {
      if (kg < 256) {
        pu0 = *(const s16x8*)(nbft + (size_t)gr * 256 + kg);
        pu1 = *(const s16x8*)(nbft + ((size_t)M + gr) * 256 + kg);
      } else {
        pu0 = *(const s16x8*)(selfb + (size_t)gr * 256 + (kg - 256));
      }
    }
  };
  auto loadB = [&](int k0) {
    #pragma unroll
    for (int i = 0; i < 4; ++i) {
      int ch = tid + i * 256;
      int m = ch >> 2, kk = (ch & 3) * 8;
      pb[i] = *(const s16x8*)(Wt + (size_t)m * 512 + k0 + kk);
    }
  };
  auto storeLDS = [&](int k0) {
    int kg = k0 + akk;
    s16x8 v = {};
    if (gr < M) {
      if (kg < 256) {
        #pragma unroll
        for (int j = 0; j < 8; ++j)
          v[j] = (short)f2bf(fmaf(a0, bf2f((unsigned short)pu0[j]),
                                  a1 * bf2f((unsigned short)pu1[j])));
      } else {
        v = pu0;
      }
    }
    *(s16x8*)&As[am * 40 + akk] = v;
    #pragma unroll
    for (int i = 0; i < 4; ++i) {
      int ch = tid + i * 256;
      int m = ch >> 2, kk = (ch & 3) * 8;
      *(s16x8*)&Bs[m * 40 + kk] = pb[i];
    }
  };

  loadA(0); loadB(0); storeLDS(0);
  __syncthreads();
  for (int k0 = 0; k0 < 512; k0 += 32) {
    int kn = k0 + 32;
    if (kn < 512) { loadA(kn); loadB(kn); }
    s16x8 af[4], bf[4];
    #pragma unroll
    for (int r = 0; r < 4; ++r)
      af[r] = *(const s16x8*)&As[(r * 16 + m16) * 40 + quad * 8];
    #pragma unroll
    for (int c = 0; c < 4; ++c)
      bf[c] = *(const s16x8*)&Bs[(w * 64 + c * 16 + m16) * 40 + quad * 8];
    #pragma unroll
    for (int r = 0; r < 4; ++r)
      #pragma unroll
      for (int c = 0; c < 4; ++c)
        acc[r][c] = __builtin_amdgcn_mfma_f32_16x16x32_bf16(af[r], bf[c], acc[r][c], 0, 0, 0);
    __syncthreads();
    if (kn < 512) {
      storeLDS(kn);
      __syncthreads();
    }
  }
  const float* __restrict__ bias = g.bias[z];
  float* __restrict__ out = g.out[z];
  #pragma unroll
  for (int r = 0; r < 4; ++r)
    #pragma unroll
    for (int i = 0; i < 4; ++i) {
      int row = row0 + r * 16 + quad * 4 + i;
      if (row < M) {
        #pragma unroll
        for (int c = 0; c < 4; ++c) {
          int col = w * 64 + c * 16 + m16;
          out[(size_t)row * 256 + col] = acc[r][c][i] + bias[col];
        }
      }
    }
}

} // namespace

extern "C" void kernel_launch(void* const* d_in, const int* in_sizes, int n_in,
                              void* d_out, int out_size, void* d_ws, size_t ws_size,
                              hipStream_t stream) {
  (void)in_sizes; (void)n_in; (void)out_size; (void)ws_size;
  const float* x[3] = {(const float*)d_in[0], (const float*)d_in[1], (const float*)d_in[2]};

  // ---- workspace layout ----
  char* p = (char*)d_ws;
  unsigned short* projfull = (unsigned short*)p;  p += (size_t)105000 * 256 * 2;
  unsigned short* nbft = (unsigned short*)p;      p += (size_t)70000 * 256 * 2;
  unsigned short* wcatbt = (unsigned short*)p;    p += (size_t)3 * 256 * 512 * 2;
  int* offs = (int*)p;                            p += (size_t)70004 * 4;
  int* counts = (int*)p;                          p += (size_t)70000 * 4;   // written by cnt2
  int* bcur = (int*)p;                            p += 160 * 4;             // zeroed
  int* ovcnt = (int*)p;                           p += 16;                  // zeroed
  int* part = (int*)p;                            p += 256;
  float* att_buf = (float*)p;                     p += (size_t)70000 * 4;
  unsigned int* csr_pay = (unsigned int*)p;       p += (size_t)1120000 * 4;
  // aliases into nbft (dead until gather_all):
  unsigned short* wshT = nbft;
  unsigned short* Wcbt = (unsigned short*)((char*)nbft + 393216);
  // record buffers alias projfull (dead until proj_mfma9 overwrites all rows):
  unsigned long long* rec2 = (unsigned long long*)projfull;            // 18 MB
  unsigned long long* ovbuf = rec2 + (size_t)NB2 * CAP2;               // 0.5 MB
  // bf16 copy of x lives in d_out (dead until final_mfma3 writes real output):
  unsigned short* xb = (unsigned short*)d_out;

  const int n_of[3] = {20000, 10000, 5000};
  const int nbt[3][2] = {{1, 2}, {0, 2}, {0, 1}};
  const int ebase[3][2] = {{3, 6}, {9, 12}, {15, 18}};
  const int nE3[3] = {320000, 160000, 80000};
  const size_t out_off[3] = {0, (size_t)20000 * 256, (size_t)30000 * 256};
  const int tstart[3] = {0, 15000, 40000};
  const int selfoff[3] = {70000, 90000, 100000};
  const int nboff[3] = {0, 40000, 60000};
  const int xboff[3] = {0, 20000, 30000};

  // ---- x -> bf16 ----
  cvt_x3<<<dim3(8750), 256, 0, stream>>>(x[0], x[1], x[2], xb);

  // ---- transpose+cvt: 3 wsh, 3 wcat ----
  Tc6 tc;
  for (int t = 0; t < 3; ++t) {
    tc.src[t] = (const float*)d_in[21 + t * 7 + 3];
    tc.dst[t] = wshT + (size_t)t * 256 * 256;
    tc.R[t] = 256;
    tc.src[3 + t] = (const float*)d_in[21 + t * 7 + 5];
    tc.dst[3 + t] = wcatbt + (size_t)t * 256 * 512;
    tc.R[3 + t] = 512;
  }
  transpose_cvt<<<dim3(8, 16, 6), 256, 0, stream>>>(tc);

  // ---- combined weights via MFMA ----
  Comb9 c9;
  for (int t = 0; t < 3; ++t) {
    int wb = 21 + t * 7;
    for (int j = 0; j < 3; ++j) {
      int combo = t * 3 + j;
      c9.A[combo] = wshT + (size_t)t * 256 * 256;
      c9.B[combo] = (const float*)d_in[wb + j];
      c9.C[combo] = Wcbt + (size_t)combo * 256 * 512;
    }
  }
  combine_mfma<<<dim3(4, 2, 9), 256, 0, stream>>>(c9);

  // ---- CSR build (LDS-staged two-level counting sort) ----
  Edges6 ep;
  const int cbase[6] = {0, 20000, 40000, 50000, 60000, 65000};
  for (int t = 0; t < 3; ++t)
    for (int r = 0; r < 2; ++r) {
      int rho = t * 2 + r, eb = ebase[t][r];
      ep.src[rho] = (const int*)d_in[eb];
      ep.dst[rho] = (const int*)d_in[eb + 1];
      ep.w[rho] = (const float*)d_in[eb + 2];
      ep.nE[rho] = nE3[t];
      ep.cbase[rho] = cbase[rho];
    }
  hipMemsetAsync(bcur, 0, 160 * 4 + 16, stream);
  bin1<<<dim3(313, 6), 256, 0, stream>>>(ep, bcur, ovcnt, rec2, ovbuf);
  cnt2<<<NB2, 256, 0, stream>>>(bcur, rec2, ovcnt, ovbuf, counts);
  scan1<<<35, 256, 0, stream>>>(counts, offs, part, 70000);
  scan2<<<1, 64, 0, stream>>>(part, 35, offs + 70000);
  scan3<<<274, 256, 0, stream>>>(offs, part, 70000);
  fine2<<<NB2, 512, 0, stream>>>(offs, bcur, rec2, ovcnt, ovbuf, csr_pay);

  // ---- all 9 projections, one launch (128x128 tiles, global_load_lds) ----
  Proj9 pj;
  for (int t = 0; t < 3; ++t) {
    int nb0 = nbt[t][0], nb1 = nbt[t][1];
    int m0 = n_of[nb0];
    pj.A[t * 3 + 0] = xb + (size_t)xboff[nb0] * 512;
    pj.C[t * 3 + 0] = projfull + (size_t)tstart[t] * 256;
    pj.M[t * 3 + 0] = m0;
    pj.A[t * 3 + 1] = xb + (size_t)xboff[nb1] * 512;
    pj.C[t * 3 + 1] = projfull + (size_t)(tstart[t] + m0) * 256;
    pj.M[t * 3 + 1] = n_of[nb1];
    pj.A[t * 3 + 2] = xb + (size_t)xboff[t] * 512;
    pj.C[t * 3 + 2] = projfull + (size_t)selfoff[t] * 256;
    pj.M[t * 3 + 2] = n_of[t];
    for (int j = 0; j < 3; ++j)
      pj.Bt[t * 3 + j] = Wcbt + (size_t)(t * 3 + j) * 256 * 512;
  }
  proj_mfma9<<<dim3(2, 157, 9), 256, 0, stream>>>(pj);

  // ---- all 6 gathers, one launch ----
  Gather6 gt;
  for (int t = 0; t < 3; ++t) {
    int m0 = n_of[nbt[t][0]];
    for (int r = 0; r < 2; ++r) {
      int rho = t * 2 + r;
      gt.proj[rho] = projfull + (size_t)(tstart[t] + (r ? m0 : 0)) * 256;
      gt.out[rho] = nbft + (size_t)(nboff[t] + r * n_of[t]) * 256;
      gt.cb[rho] = cbase[rho];
      gt.n[rho] = n_of[t];
    }
  }
  gather_all<<<dim3(5000, 6), 256, 0, stream>>>(gt, offs, csr_pay);

  // ---- attention (3 types) ----
  Att3 at;
  for (int t = 0; t < 3; ++t) {
    at.nb[t] = nbft + (size_t)nboff[t] * 256;
    at.self[t] = projfull + (size_t)selfoff[t] * 256;
    at.watt[t] = (const float*)d_in[21 + t * 7 + 4];
    at.att[t] = att_buf + nboff[t];
    at.n[t] = n_of[t];
  }
  e_att3<<<dim3(10000, 1, 3), 256, 0, stream>>>(at);

  // ---- final GEMM (3 types, BM=64, 64x64 wave tiles) ----
  Fin3 fn;
  for (int t = 0; t < 3; ++t) {
    fn.nb[t] = nbft + (size_t)nboff[t] * 256;
    fn.self[t] = projfull + (size_t)selfoff[t] * 256;
    fn.att[t] = att_buf + nboff[t];
    fn.Wt[t] = wcatbt + (size_t)t * 256 * 512;
    fn.bias[t] = (const float*)d_in[21 + t * 7 + 6];
    fn.out[t] = (float*)d_out + out_off[t];
    fn.M[t] = n_of[t];
  }
  final_mfma3<<<dim3(1, 313, 3), 256, 0, stream>>>(fn);
}